// Round 14
// baseline (553.713 us; speedup 1.0000x reference)
//
#include <hip/hip_runtime.h>
#include <hip/hip_bf16.h>

typedef __attribute__((ext_vector_type(8)))  short   s16x8;
typedef __attribute__((ext_vector_type(8)))  __bf16  bf16x8;
typedef __attribute__((ext_vector_type(4)))  float   f32x4;
typedef __attribute__((ext_vector_type(16))) float   f32x16;

#define DEV static __device__ __forceinline__

DEV short f2bf(float f) {
  unsigned u = __builtin_bit_cast(unsigned, f);
  u = (u + 0x7fff + ((u >> 16) & 1)) >> 16;
  return (short)u;
}
DEV float bf2f(short s) {
  unsigned u = ((unsigned)(unsigned short)s) << 16;
  return __builtin_bit_cast(float, u);
}

DEV void gload16(const void* g, void* l) {
  __builtin_amdgcn_global_load_lds(
      (const __attribute__((address_space(1))) unsigned int*)g,
      (__attribute__((address_space(3))) unsigned int*)l, 16, 0, 0);
}

DEV unsigned cvtpk(float lo, float hi) {
  unsigned r;
  asm("v_cvt_pk_bf16_f32 %0, %1, %2" : "=v"(r) : "v"(lo), "v"(hi));
  return r;
}

typedef union { unsigned u[4]; bf16x8 v; } BW;

// ---------------- fused cast fp32 -> bf16 for all 5 inputs ------------------
__global__ __launch_bounds__(256) void cast_all(
    const float* __restrict__ x,  const float* __restrict__ wq,
    const float* __restrict__ wk, const float* __restrict__ wv,
    const float* __restrict__ wo,
    short* __restrict__ xb, short* __restrict__ wqkvb, short* __restrict__ wob) {
  long i = (long)blockIdx.x * 256 + threadIdx.x;  // vector index
  const float* src;
  short* dst;
  long off;
  if (i < 2097152)       { src = x;  dst = xb;               off = i; }
  else if (i < 4194304)  { src = wq; dst = wqkvb;            off = i - 2097152; }
  else if (i < 4718592)  { src = wk; dst = wqkvb + 16777216; off = i - 4194304; }
  else if (i < 5242880)  { src = wv; dst = wqkvb + 20971520; off = i - 4718592; }
  else                   { src = wo; dst = wob;              off = i - 5242880; }
  long e = off * 8;
  float4 a = *(const float4*)(src + e);
  float4 b = *(const float4*)(src + e + 4);
  s16x8 o;
  o[0] = f2bf(a.x); o[1] = f2bf(a.y); o[2] = f2bf(a.z); o[3] = f2bf(a.w);
  o[4] = f2bf(b.x); o[5] = f2bf(b.y); o[6] = f2bf(b.z); o[7] = f2bf(b.w);
  *(s16x8*)(dst + e) = o;
}

// ---------------- GEMM-Q: 256x256 8-phase (proven), q + RoPE epilogue -------
__global__ __launch_bounds__(512, 2) void gemm_q(
    const short* __restrict__ A, const short* __restrict__ W,
    short* __restrict__ qb)
{
  __shared__ __align__(16) short lds[2][2][16384];  // [buf][0=A,1=B]

  const int tid = threadIdx.x;
  const int lane = tid & 63;
  const int w = tid >> 6;
  const int wm = w >> 2, wn = w & 3;          // 2M x 4N waves
  const int l15 = lane & 15, lg = lane >> 4;
  const int swz = (l15 & 7) << 4;

  int c = blockIdx.x & 7, j = blockIdx.x >> 3;
  const int tm = (c >> 2) * 8 + (j & 7);
  const int tn = (c & 3) * 4 + (j >> 3);

  const char* Ac = (const char*)A;
  const char* Wc = (const char*)W;

  int qXo[4];
  long aQ[4], bQ[4];
  #pragma unroll
  for (int q = 0; q < 4; ++q) {
    int X = q * 8192 + tid * 16;
    int row = X >> 7;
    int colS = (X & 127) ^ ((row & 7) << 4);
    qXo[q] = X;
    aQ[q] = (long)(tm * 256 + row) * 8192 + colS;
    bQ[q] = (long)(tn * 256 + row) * 8192 + colS;
  }

#define SA(TT, BB, Q)                                                        \
  if ((TT) < 64) gload16(Ac + aQ[Q] + (long)(TT) * 128,                      \
                         (char*)&lds[BB][0][0] + qXo[Q]);
#define SB(TT, BB, Q)                                                        \
  if ((TT) < 64) gload16(Wc + bQ[Q] + (long)(TT) * 128,                      \
                         (char*)&lds[BB][1][0] + qXo[Q]);

  f32x4 zero = {0.f, 0.f, 0.f, 0.f};
  f32x4 acc[8][4];
  #pragma unroll
  for (int i = 0; i < 8; ++i)
    #pragma unroll
    for (int jj = 0; jj < 4; ++jj) acc[i][jj] = zero;

  const int aro = (wm * 128 + l15) * 128;
  const int bro = (wn * 64 + l15) * 128;
  const int cs0 = (lg << 4) ^ swz;
  const int cs1 = (64 | (lg << 4)) ^ swz;

  SB(0, 0, 0) SB(0, 0, 1) SB(0, 0, 2) SB(0, 0, 3)
  SA(0, 0, 0) SA(0, 0, 1) SA(0, 0, 2) SA(0, 0, 3)
  asm volatile("s_waitcnt vmcnt(0)" ::: "memory");
  __builtin_amdgcn_s_barrier();

  #pragma clang loop unroll(disable)
  for (int t = 0; t < 64; ++t) {
    const int bt = t & 1, nb = bt ^ 1;
    const char* LA = (const char*)&lds[bt][0][0];
    const char* LB = (const char*)&lds[bt][1][0];
    bf16x8 af[4][2], bf0[2][2], bf1[2][2];

    // ---- phase 0 ----
    #pragma unroll
    for (int i = 0; i < 4; ++i) {
      af[i][0] = *(const bf16x8*)(LA + aro + i * 2048 + cs0);
      af[i][1] = *(const bf16x8*)(LA + aro + i * 2048 + cs1);
    }
    #pragma unroll
    for (int jj = 0; jj < 2; ++jj) {
      bf0[jj][0] = *(const bf16x8*)(LB + bro + jj * 2048 + cs0);
      bf0[jj][1] = *(const bf16x8*)(LB + bro + jj * 2048 + cs1);
    }
    SB(t + 1, nb, 0) SB(t + 1, nb, 1) SA(t + 1, nb, 0) SA(t + 1, nb, 2)
    __builtin_amdgcn_s_barrier();
    asm volatile("s_waitcnt lgkmcnt(0)" ::: "memory");
    __builtin_amdgcn_sched_barrier(0);
    __builtin_amdgcn_s_setprio(1);
    #pragma unroll
    for (int i = 0; i < 4; ++i)
      #pragma unroll
      for (int jj = 0; jj < 2; ++jj) {
        acc[i][jj] = __builtin_amdgcn_mfma_f32_16x16x32_bf16(af[i][0], bf0[jj][0], acc[i][jj], 0, 0, 0);
        acc[i][jj] = __builtin_amdgcn_mfma_f32_16x16x32_bf16(af[i][1], bf0[jj][1], acc[i][jj], 0, 0, 0);
      }
    __builtin_amdgcn_s_setprio(0);
    __builtin_amdgcn_s_barrier();

    // ---- phase 1 ----
    #pragma unroll
    for (int jj = 0; jj < 2; ++jj) {
      bf1[jj][0] = *(const bf16x8*)(LB + bro + (2 + jj) * 2048 + cs0);
      bf1[jj][1] = *(const bf16x8*)(LB + bro + (2 + jj) * 2048 + cs1);
    }
    SB(t + 1, nb, 2) SB(t + 1, nb, 3) SA(t + 1, nb, 1) SA(t + 1, nb, 3)
    __builtin_amdgcn_s_barrier();
    asm volatile("s_waitcnt lgkmcnt(0)" ::: "memory");
    __builtin_amdgcn_sched_barrier(0);
    __builtin_amdgcn_s_setprio(1);
    #pragma unroll
    for (int i = 0; i < 4; ++i)
      #pragma unroll
      for (int jj = 0; jj < 2; ++jj) {
        acc[i][2 + jj] = __builtin_amdgcn_mfma_f32_16x16x32_bf16(af[i][0], bf1[jj][0], acc[i][2 + jj], 0, 0, 0);
        acc[i][2 + jj] = __builtin_amdgcn_mfma_f32_16x16x32_bf16(af[i][1], bf1[jj][1], acc[i][2 + jj], 0, 0, 0);
      }
    __builtin_amdgcn_s_setprio(0);
    if (t == 63) {
      asm volatile("s_waitcnt vmcnt(0)" ::: "memory");
    } else {
      asm volatile("s_waitcnt vmcnt(8)" ::: "memory");
    }
    __builtin_amdgcn_sched_barrier(0);
    __builtin_amdgcn_s_barrier();

    // ---- phase 2 ----
    #pragma unroll
    for (int i = 0; i < 4; ++i) {
      af[i][0] = *(const bf16x8*)(LA + aro + (4 + i) * 2048 + cs0);
      af[i][1] = *(const bf16x8*)(LA + aro + (4 + i) * 2048 + cs1);
    }
    __builtin_amdgcn_s_barrier();
    asm volatile("s_waitcnt lgkmcnt(0)" ::: "memory");
    __builtin_amdgcn_sched_barrier(0);
    __builtin_amdgcn_s_setprio(1);
    #pragma unroll
    for (int i = 0; i < 4; ++i)
      #pragma unroll
      for (int jj = 0; jj < 2; ++jj) {
        acc[4 + i][jj] = __builtin_amdgcn_mfma_f32_16x16x32_bf16(af[i][0], bf0[jj][0], acc[4 + i][jj], 0, 0, 0);
        acc[4 + i][jj] = __builtin_amdgcn_mfma_f32_16x16x32_bf16(af[i][1], bf0[jj][1], acc[4 + i][jj], 0, 0, 0);
      }
    __builtin_amdgcn_s_setprio(0);
    __builtin_amdgcn_s_barrier();

    // ---- phase 3 ----
    __builtin_amdgcn_s_setprio(1);
    #pragma unroll
    for (int i = 0; i < 4; ++i)
      #pragma unroll
      for (int jj = 0; jj < 2; ++jj) {
        acc[4 + i][2 + jj] = __builtin_amdgcn_mfma_f32_16x16x32_bf16(af[i][0], bf1[jj][0], acc[4 + i][2 + jj], 0, 0, 0);
        acc[4 + i][2 + jj] = __builtin_amdgcn_mfma_f32_16x16x32_bf16(af[i][1], bf1[jj][1], acc[4 + i][2 + jj], 0, 0, 0);
      }
    __builtin_amdgcn_s_setprio(0);
    if (t < 63) {
      asm volatile("s_waitcnt vmcnt(2)" ::: "memory");
      __builtin_amdgcn_sched_barrier(0);
      __builtin_amdgcn_s_barrier();
    }
  }
#undef SA
#undef SB

  // epilogue: all columns are q -> RoPE (pair = adjacent l15 lane) + write qb
  #pragma unroll
  for (int mr = 0; mr < 8; ++mr) {
    int mbase = tm * 256 + wm * 128 + mr * 16 + lg * 4;
    #pragma unroll
    for (int nr = 0; nr < 4; ++nr) {
      int col = tn * 256 + wn * 64 + nr * 16 + l15;
      float pv[4];
      #pragma unroll
      for (int r = 0; r < 4; ++r) pv[r] = __shfl_xor(acc[mr][nr][r], 1);
      #pragma unroll
      for (int r = 0; r < 4; ++r) {
        int m = mbase + r;
        float v = acc[mr][nr][r];
        int b = m >> 11, s = m & 2047;
        int h = col >> 7, d = col & 127;
        float x1 = (l15 & 1) ? pv[r] : v;
        float x2 = (l15 & 1) ? v : pv[r];
        float inv = __expf(-0.14391157f * (float)(d >> 1));  // 1e4^(-2j/128)
        float sn, cs;
        __sincosf((float)s * inv, &sn, &cs);
        float rr = (l15 & 1) ? (x1 * sn + x2 * cs) : (x1 * cs - x2 * sn);
        qb[((long)((b * 32 + h) * 2048 + s)) * 128 + d] = f2bf(rr);
      }
    }
  }
}

// ---------------- GEMM-KV: 256x128, BK=64, 3-buffer (proven), N=2048 --------
__global__ __launch_bounds__(512, 2) void gemm_kv(
    const short* __restrict__ A, const short* __restrict__ W,
    short* __restrict__ kb, short* __restrict__ vb,
    float* __restrict__ nk, float* __restrict__ nv)
{
  __shared__ short lds[3][24576];  // 3 x 48KB: A at +0 (32KB), B at +32768

  const int tid = threadIdx.x;
  const int lane = tid & 63;
  const int w = tid >> 6;
  const int wm = w >> 1, wn = w & 1;          // 4 x 2 waves
  const int l15 = lane & 15, lg = lane >> 4;
  const int swz = (l15 & 7) << 4;

  int c = blockIdx.x & 7, j = blockIdx.x >> 3;
  const int tm = (c >> 2) * 8 + (j & 7);
  const int tn = (c & 3) * 4 + (j >> 3);     // 16 tn tiles of 128

  const char* Ac = (const char*)A;
  const char* Wc = (const char*)W;

  int aXo[4], bXo[2];
  long aSrc[4], bSrc[2];
  #pragma unroll
  for (int l4 = 0; l4 < 4; ++l4) {
    int X = tid * 16 + l4 * 8192;
    int row = X >> 7;
    int colS = (X & 127) ^ (((X >> 7) & 7) << 4);
    aXo[l4] = X;
    aSrc[l4] = (long)(tm * 256 + row) * 8192 + colS;
  }
  #pragma unroll
  for (int l4 = 0; l4 < 2; ++l4) {
    int X = tid * 16 + l4 * 8192;
    int row = X >> 7;
    int colS = (X & 127) ^ (((X >> 7) & 7) << 4);
    bXo[l4] = X;
    bSrc[l4] = (long)(tn * 128 + row) * 8192 + colS;
  }

#define STAGE(TT, BI)                                                        \
  {                                                                          \
    const long kof_ = (long)(TT) * 128;                                      \
    _Pragma("unroll")                                                        \
    for (int l4 = 0; l4 < 4; ++l4)                                           \
      gload16(Ac + aSrc[l4] + kof_, (char*)&lds[BI][0] + aXo[l4]);           \
    _Pragma("unroll")                                                        \
    for (int l4 = 0; l4 < 2; ++l4)                                           \
      gload16(Wc + bSrc[l4] + kof_, (char*)&lds[BI][0] + 32768 + bXo[l4]);   \
  }

  f32x4 zero = {0.f, 0.f, 0.f, 0.f};
  f32x4 acc[4][4];
  #pragma unroll
  for (int i = 0; i < 4; ++i)
    #pragma unroll
    for (int jj = 0; jj < 4; ++jj) acc[i][jj] = zero;

  const int aro = (wm * 64 + l15) * 128;
  const int bro = 32768 + (wn * 64 + l15) * 128;
  const int cs0 = (lg << 4) ^ swz;
  const int cs1 = (64 | (lg << 4)) ^ swz;

#define MF(a0, a1, MR)                                                       \
  __builtin_amdgcn_s_setprio(1);                                             \
  _Pragma("unroll")                                                          \
  for (int nr = 0; nr < 4; ++nr) {                                           \
    acc[MR][nr] = __builtin_amdgcn_mfma_f32_16x16x32_bf16(                   \
        a0, bfr[nr][0], acc[MR][nr], 0, 0, 0);                               \
    acc[MR][nr] = __builtin_amdgcn_mfma_f32_16x16x32_bf16(                   \
        a1, bfr[nr][1], acc[MR][nr], 0, 0, 0);                               \
  }                                                                          \
  __builtin_amdgcn_s_setprio(0);

#define TILE(T, BI)                                                          \
  {                                                                          \
    const char* L = (const char*)&lds[BI][0];                                \
    bf16x8 bfr[4][2];                                                        \
    _Pragma("unroll")                                                        \
    for (int nr = 0; nr < 4; ++nr) {                                         \
      bfr[nr][0] = *(const bf16x8*)(L + bro + nr * 2048 + cs0);              \
      bfr[nr][1] = *(const bf16x8*)(L + bro + nr * 2048 + cs1);              \
    }                                                                        \
    bf16x8 g0, g1, h0, h1;                                                   \
    g0 = *(const bf16x8*)(L + aro + 0 * 2048 + cs0);                         \
    g1 = *(const bf16x8*)(L + aro + 0 * 2048 + cs1);                         \
    h0 = *(const bf16x8*)(L + aro + 1 * 2048 + cs0);                         \
    h1 = *(const bf16x8*)(L + aro + 1 * 2048 + cs1);                         \
    asm volatile("s_waitcnt lgkmcnt(2)" ::: "memory");                       \
    __builtin_amdgcn_sched_barrier(0);                                       \
    MF(g0, g1, 0)                                                            \
    g0 = *(const bf16x8*)(L + aro + 2 * 2048 + cs0);                         \
    g1 = *(const bf16x8*)(L + aro + 2 * 2048 + cs1);                         \
    asm volatile("s_waitcnt lgkmcnt(2)" ::: "memory");                       \
    __builtin_amdgcn_sched_barrier(0);                                       \
    MF(h0, h1, 1)                                                            \
    h0 = *(const bf16x8*)(L + aro + 3 * 2048 + cs0);                         \
    h1 = *(const bf16x8*)(L + aro + 3 * 2048 + cs1);                         \
    asm volatile("s_waitcnt lgkmcnt(2)" ::: "memory");                       \
    __builtin_amdgcn_sched_barrier(0);                                       \
    MF(g0, g1, 2)                                                            \
    asm volatile("s_waitcnt lgkmcnt(0)" ::: "memory");                       \
    __builtin_amdgcn_sched_barrier(0);                                       \
    MF(h0, h1, 3)                                                            \
    if ((T) < 62) {                                                          \
      asm volatile("s_waitcnt vmcnt(6)" ::: "memory");                       \
    } else if ((T) == 62) {                                                  \
      asm volatile("s_waitcnt vmcnt(0)" ::: "memory");                       \
    }                                                                        \
    if ((T) < 63) __builtin_amdgcn_s_barrier();                              \
    if ((T) < 61) { STAGE((T) + 3, BI) }                                     \
  }

  STAGE(0, 0)
  STAGE(1, 1)
  STAGE(2, 2)
  asm volatile("s_waitcnt vmcnt(12)" ::: "memory");
  __builtin_amdgcn_s_barrier();

  #pragma clang loop unroll(disable)
  for (int t3 = 0; t3 < 63; t3 += 3) {
    TILE(t3 + 0, 0)
    TILE(t3 + 1, 1)
    TILE(t3 + 2, 2)
  }
  TILE(63, 0)

#undef STAGE
#undef TILE
#undef MF

  // epilogue: col 0..1023 = k (RoPE + nk), 1024..2047 = v (nv + vb^T)
  #pragma unroll
  for (int mr = 0; mr < 4; ++mr) {
    int mbase = tm * 256 + wm * 64 + mr * 16 + lg * 4;
    #pragma unroll
    for (int nr = 0; nr < 4; ++nr) {
      int col = tn * 128 + wn * 64 + nr * 16 + l15;
      float pv[4];
      #pragma unroll
      for (int r = 0; r < 4; ++r) pv[r] = __shfl_xor(acc[mr][nr][r], 1);
      #pragma unroll
      for (int r = 0; r < 4; ++r) {
        int m = mbase + r;
        float v = acc[mr][nr][r];
        int b = m >> 11, s = m & 2047;
        if (col < 1024) {  // k: RoPE
          int h = col >> 7, d = col & 127;
          float x1 = (l15 & 1) ? pv[r] : v;
          float x2 = (l15 & 1) ? v : pv[r];
          float inv = __expf(-0.14391157f * (float)(d >> 1));
          float sn, cs;
          __sincosf((float)s * inv, &sn, &cs);
          float rr = (l15 & 1) ? (x1 * sn + x2 * cs) : (x1 * cs - x2 * sn);
          long o = ((long)((b * 8 + h) * 2048 + s)) * 128 + d;
          kb[o] = f2bf(rr);
          nk[o] = v;  // PRE-rope
        } else {
          int c2 = col - 1024;
          int h = c2 >> 7, d = c2 & 127;
          long o = ((long)((b * 8 + h) * 2048 + s)) * 128 + d;
          nv[o] = v;
          vb[((long)((b * 8 + h) * 128 + d)) * 2048 + s] = f2bf(v);  // [b][hkv][d][s]
        }
      }
    }
  }
}

// ---------------- GEMM2: out-proj. 256x256, 8-phase (proven) ----------------
__global__ __launch_bounds__(512, 2) void gemm_out(
    const short* __restrict__ A, const short* __restrict__ W,
    float* __restrict__ Cout)
{
  __shared__ __align__(16) short lds[2][2][16384];  // [buf][0=A,1=B]

  const int tid = threadIdx.x;
  const int lane = tid & 63;
  const int w = tid >> 6;
  const int wm = w >> 2, wn = w & 3;
  const int l15 = lane & 15, lg = lane >> 4;
  const int swz = (l15 & 7) << 4;

  int c = blockIdx.x & 7, j = blockIdx.x >> 3;
  const int tm = (c >> 2) * 8 + (j & 7);
  const int tn = (c & 3) * 4 + (j >> 3);

  const char* Ac = (const char*)A;
  const char* Wc = (const char*)W;

  int qXo[4];
  long aQ[4], bQ[4];
  #pragma unroll
  for (int q = 0; q < 4; ++q) {
    int X = q * 8192 + tid * 16;
    int row = X >> 7;
    int colS = (X & 127) ^ ((row & 7) << 4);
    qXo[q] = X;
    aQ[q] = (long)(tm * 256 + row) * 8192 + colS;
    bQ[q] = (long)(tn * 256 + row) * 8192 + colS;
  }

#define SA(TT, BB, Q)                                                        \
  if ((TT) < 64) gload16(Ac + aQ[Q] + (long)(TT) * 128,                      \
                         (char*)&lds[BB][0][0] + qXo[Q]);
#define SB(TT, BB, Q)                                                        \
  if ((TT) < 64) gload16(Wc + bQ[Q] + (long)(TT) * 128,                      \
                         (char*)&lds[BB][1][0] + qXo[Q]);

  f32x4 zero = {0.f, 0.f, 0.f, 0.f};
  f32x4 acc[8][4];
  #pragma unroll
  for (int i = 0; i < 8; ++i)
    #pragma unroll
    for (int jj = 0; jj < 4; ++jj) acc[i][jj] = zero;

  const int aro = (wm * 128 + l15) * 128;
  const int bro = (wn * 64 + l15) * 128;
  const int cs0 = (lg << 4) ^ swz;
  const int cs1 = (64 | (lg << 4)) ^ swz;

  SB(0, 0, 0) SB(0, 0, 1) SB(0, 0, 2) SB(0, 0, 3)
  SA(0, 0, 0) SA(0, 0, 1) SA(0, 0, 2) SA(0, 0, 3)
  asm volatile("s_waitcnt vmcnt(0)" ::: "memory");
  __builtin_amdgcn_s_barrier();

  #pragma clang loop unroll(disable)
  for (int t = 0; t < 64; ++t) {
    const int bt = t & 1, nb = bt ^ 1;
    const char* LA = (const char*)&lds[bt][0][0];
    const char* LB = (const char*)&lds[bt][1][0];
    bf16x8 af[4][2], bf0[2][2], bf1[2][2];

    #pragma unroll
    for (int i = 0; i < 4; ++i) {
      af[i][0] = *(const bf16x8*)(LA + aro + i * 2048 + cs0);
      af[i][1] = *(const bf16x8*)(LA + aro + i * 2048 + cs1);
    }
    #pragma unroll
    for (int jj = 0; jj < 2; ++jj) {
      bf0[jj][0] = *(const bf16x8*)(LB + bro + jj * 2048 + cs0);
      bf0[jj][1] = *(const bf16x8*)(LB + bro + jj * 2048 + cs1);
    }
    SB(t + 1, nb, 0) SB(t + 1, nb, 1) SA(t + 1, nb, 0) SA(t + 1, nb, 2)
    __builtin_amdgcn_s_barrier();
    asm volatile("s_waitcnt lgkmcnt(0)" ::: "memory");
    __builtin_amdgcn_sched_barrier(0);
    __builtin_amdgcn_s_setprio(1);
    #pragma unroll
    for (int i = 0; i < 4; ++i)
      #pragma unroll
      for (int jj = 0; jj < 2; ++jj) {
        acc[i][jj] = __builtin_amdgcn_mfma_f32_16x16x32_bf16(af[i][0], bf0[jj][0], acc[i][jj], 0, 0, 0);
        acc[i][jj] = __builtin_amdgcn_mfma_f32_16x16x32_bf16(af[i][1], bf0[jj][1], acc[i][jj], 0, 0, 0);
      }
    __builtin_amdgcn_s_setprio(0);
    __builtin_amdgcn_s_barrier();

    #pragma unroll
    for (int jj = 0; jj < 2; ++jj) {
      bf1[jj][0] = *(const bf16x8*)(LB + bro + (2 + jj) * 2048 + cs0);
      bf1[jj][1] = *(const bf16x8*)(LB + bro + (2 + jj) * 2048 + cs1);
    }
    SB(t + 1, nb, 2) SB(t + 1, nb, 3) SA(t + 1, nb, 1) SA(t + 1, nb, 3)
    __builtin_amdgcn_s_barrier();
    asm volatile("s_waitcnt lgkmcnt(0)" ::: "memory");
    __builtin_amdgcn_sched_barrier(0);
    __builtin_amdgcn_s_setprio(1);
    #pragma unroll
    for (int i = 0; i < 4; ++i)
      #pragma unroll
      for (int jj = 0; jj < 2; ++jj) {
        acc[i][2 + jj] = __builtin_amdgcn_mfma_f32_16x16x32_bf16(af[i][0], bf1[jj][0], acc[i][2 + jj], 0, 0, 0);
        acc[i][2 + jj] = __builtin_amdgcn_mfma_f32_16x16x32_bf16(af[i][1], bf1[jj][1], acc[i][2 + jj], 0, 0, 0);
      }
    __builtin_amdgcn_s_setprio(0);
    if (t == 63) {
      asm volatile("s_waitcnt vmcnt(0)" ::: "memory");
    } else {
      asm volatile("s_waitcnt vmcnt(8)" ::: "memory");
    }
    __builtin_amdgcn_sched_barrier(0);
    __builtin_amdgcn_s_barrier();

    #pragma unroll
    for (int i = 0; i < 4; ++i) {
      af[i][0] = *(const bf16x8*)(LA + aro + (4 + i) * 2048 + cs0);
      af[i][1] = *(const bf16x8*)(LA + aro + (4 + i) * 2048 + cs1);
    }
    __builtin_amdgcn_s_barrier();
    asm volatile("s_waitcnt lgkmcnt(0)" ::: "memory");
    __builtin_amdgcn_sched_barrier(0);
    __builtin_amdgcn_s_setprio(1);
    #pragma unroll
    for (int i = 0; i < 4; ++i)
      #pragma unroll
      for (int jj = 0; jj < 2; ++jj) {
        acc[4 + i][jj] = __builtin_amdgcn_mfma_f32_16x16x32_bf16(af[i][0], bf0[jj][0], acc[4 + i][jj], 0, 0, 0);
        acc[4 + i][jj] = __builtin_amdgcn_mfma_f32_16x16x32_bf16(af[i][1], bf0[jj][1], acc[4 + i][jj], 0, 0, 0);
      }
    __builtin_amdgcn_s_setprio(0);
    __builtin_amdgcn_s_barrier();

    __builtin_amdgcn_s_setprio(1);
    #pragma unroll
    for (int i = 0; i < 4; ++i)
      #pragma unroll
      for (int jj = 0; jj < 2; ++jj) {
        acc[4 + i][2 + jj] = __builtin_amdgcn_mfma_f32_16x16x32_bf16(af[i][0], bf1[jj][0], acc[4 + i][2 + jj], 0, 0, 0);
        acc[4 + i][2 + jj] = __builtin_amdgcn_mfma_f32_16x16x32_bf16(af[i][1], bf1[jj][1], acc[4 + i][2 + jj], 0, 0, 0);
      }
    __builtin_amdgcn_s_setprio(0);
    if (t < 63) {
      asm volatile("s_waitcnt vmcnt(2)" ::: "memory");
      __builtin_amdgcn_sched_barrier(0);
      __builtin_amdgcn_s_barrier();
    }
  }
#undef SA
#undef SB

  #pragma unroll
  for (int mr = 0; mr < 8; ++mr) {
    int mbase = tm * 256 + wm * 128 + mr * 16 + lg * 4;
    #pragma unroll
    for (int nr = 0; nr < 4; ++nr) {
      int col = tn * 256 + wn * 64 + nr * 16 + l15;
      #pragma unroll
      for (int r = 0; r < 4; ++r)
        Cout[(long)(mbase + r) * 4096 + col] = acc[mr][nr][r];
    }
  }
}

// ---------------- Flash attention v6: 3 blocks/CU (48KB LDS), T14 V-regs ----
// grid 1024, 256 thr. K double-buffered LDS (gload_lds, swizzle (row&15)<<4);
// V single-buffered LDS, prefetched to REGISTERS (linear, coalesced) at iter
// start, ds_written (swizzled (row&7)<<4) after the post-PV barrier.
// 2 barriers/iter; compiler vmcnt/lgkm drains at each barrier cover all
// staging. Masked waves skip compute only (uniform guards, barriers balanced).
__global__ __launch_bounds__(256) void flash_kernel(
    const short* __restrict__ qb, const short* __restrict__ kb,
    const short* __restrict__ vt, short* __restrict__ ao)
{
  const int bid = blockIdx.x;
  const int qt = 15 - (bid >> 6);   // LPT: heaviest blocks dispatch first
  const int hb = bid & 63;
  const int h = hb & 31, b = hb >> 5;
  const int hkv = h >> 2;
  const int tid = threadIdx.x, w = tid >> 6, lane = tid & 63;
  const int l31 = lane & 31, hi = lane >> 5;
  const int hi16 = hi * 16;
  const int q0 = qt * 128 + w * 32;
  const int q_abs = q0 + l31;

  const short* Q  = qb + (long)(b * 32 + h) * 2048 * 128;
  const char*  Kg = (const char*)(kb + (long)(b * 8 + hkv) * 2048 * 128);
  const char*  Vg = (const char*)(vt + (long)(b * 8 + hkv) * 2048 * 128);  // [d][s]

  __shared__ short Ks[2][64 * 128];  // 32KB: [kv][d], swizzled (row&15)<<4
  __shared__ short Vs[128 * 64];     // 16KB: [d][kv], swizzled (row&7)<<4

  // K staging (pre-swizzled source, linear dest); V reg-staging offsets
  int skX[4], Xo[4], vXs[4];
  long vSrc[4];
  #pragma unroll
  for (int i2 = 0; i2 < 4; ++i2) {
    int X = tid * 16 + i2 * 4096;
    Xo[i2] = X;
    skX[i2] = X ^ (((X >> 8) & 15) << 4);
    vXs[i2] = X ^ (((X >> 7) & 7) << 4);           // swizzled LDS dest
    vSrc[i2] = (long)(X >> 7) * 4096 + (X & 127);  // linear global (+kv*2)
  }

  bf16x8 qf[8];
  #pragma unroll
  for (int c = 0; c < 8; ++c)
    qf[c] = *(const bf16x8*)&Q[(long)q_abs * 128 + c * 16 + hi * 8];

  f32x16 o[4];
  #pragma unroll
  for (int db = 0; db < 4; ++db)
    #pragma unroll
    for (int r = 0; r < 16; ++r) o[db][r] = 0.f;
  float m_ = -3e38f, l_ = 0.f;

  const float scale2 = 0.08838834764831845f * 1.4426950408889634f;
  const int nt = 2 * (qt + 1);
  const int kswk = (l31 & 15) << 4;
  const int kswv = (l31 & 7) << 4;

  // prologue: K(0) -> Ks[0]; V(0) -> regs -> Vs
  #pragma unroll
  for (int i2 = 0; i2 < 4; ++i2) gload16(Kg + skX[i2], (char*)Ks[0] + Xo[i2]);
  {
    s16x8 vr0 = *(const s16x8*)(Vg + vSrc[0]);
    s16x8 vr1 = *(const s16x8*)(Vg + vSrc[1]);
    s16x8 vr2 = *(const s16x8*)(Vg + vSrc[2]);
    s16x8 vr3 = *(const s16x8*)(Vg + vSrc[3]);
    *(s16x8*)((char*)Vs + vXs[0]) = vr0;
    *(s16x8*)((char*)Vs + vXs[1]) = vr1;
    *(s16x8*)((char*)Vs + vXs[2]) = vr2;
    *(s16x8*)((char*)Vs + vXs[3]) = vr3;
  }
  __syncthreads();  // drains vmcnt (K landed) + lgkm; publishes Vs

  for (int t = 0; t < nt; ++t) {
    const int kv0 = t * 64;
    const int cur = t & 1;
    const bool live = (kv0 <= q0 + 31);
    s16x8 vr0, vr1, vr2, vr3;
    if (t + 1 < nt) {  // stage K(t+1) -> LDS; V(t+1) -> regs (hidden by compute)
      const long kvb = (long)(kv0 + 64);
      #pragma unroll
      for (int i2 = 0; i2 < 4; ++i2)
        gload16(Kg + kvb * 256 + skX[i2], (char*)Ks[cur ^ 1] + Xo[i2]);
      vr0 = *(const s16x8*)(Vg + kvb * 2 + vSrc[0]);
      vr1 = *(const s16x8*)(Vg + kvb * 2 + vSrc[1]);
      vr2 = *(const s16x8*)(Vg + kvb * 2 + vSrc[2]);
      vr3 = *(const s16x8*)(Vg + kvb * 2 + vSrc[3]);
    }

    if (live) {
      f32x16 s0, s1;
      #pragma unroll
      for (int r = 0; r < 16; ++r) { s0[r] = 0.f; s1[r] = 0.f; }
      const char* kbase = (const char*)Ks[cur] + l31 * 256;
      __builtin_amdgcn_s_setprio(1);
      #pragma unroll
      for (int c = 0; c < 8; ++c) {
        bf16x8 kf0 = *(const bf16x8*)(kbase + ((c * 32 + hi16) ^ kswk));
        bf16x8 kf1 = *(const bf16x8*)(kbase + 8192 + ((c * 32 + hi16) ^ kswk));
        s0 = __builtin_amdgcn_mfma_f32_32x32x16_bf16(kf0, qf[c], s0, 0, 0, 0);
        s1 = __builtin_amdgcn_mfma_f32_32x32x16_bf16(kf1, qf[c], s1, 0, 0, 0);
      }
      __builtin_amdgcn_s_setprio(0);

      const bool diag = (kv0 + 63 > q0);
      if (diag) {
        #pragma unroll
        for (int r = 0; r < 16; ++r) {
          int krow = (r & 3) + 8 * (r >> 2) + 4 * hi;
          if (kv0 + krow > q_abs)      s0[r] = -3e38f;
          if (kv0 + 32 + krow > q_abs) s1[r] = -3e38f;
        }
      }
      float mx = fmaxf(s0[0], s1[0]);
      #pragma unroll
      for (int r = 1; r < 16; ++r) mx = fmaxf(mx, fmaxf(s0[r], s1[r]));
      mx *= scale2;
      mx = fmaxf(mx, __shfl_xor(mx, 32));
      int need = mx > m_ + 11.5f;
      if (__any(need)) {
        float mn = fmaxf(m_, mx);
        float fac = exp2f(m_ - mn);
        m_ = mn;
        l_ *= fac;
        #pragma unroll
        for (int db = 0; db < 4; ++db)
          #pragma unroll
          for (int r = 0; r < 16; ++r) o[db][r] *= fac;
      }
      float rs = 0.f;
      #pragma unroll
      for (int r = 0; r < 16; ++r) {
        float p0 = exp2f(fmaf(s0[r], scale2, -m_));
        float p1 = exp2f(fmaf(s1[r], scale2, -m_));
        s0[r] = p0; s1[r] = p1;
        rs += p0 + p1;
      }
      rs += __shfl_xor(rs, 32);
      l_ += rs;

      const char* vbase = (const char*)Vs + l31 * 128;
      #pragma unroll
      for (int t2 = 0; t2 < 2; ++t2) {
        const f32x16 sp = t2 ? s1 : s0;
        unsigned wd[8];
        #pragma unroll
        for (int jj = 0; jj < 8; ++jj) wd[jj] = cvtpk(sp[2 * jj], sp[2 * jj + 1]);
        unsigned u0 = hi ? wd[0] : wd[2];
        unsigned u1 = hi ? wd[1] : wd[3];
        unsigned u2 = hi ? wd[4] : wd[6];
        unsigned u3 = hi ? wd[5] : wd[7];
        unsigned x0 = (unsigned)__shfl_xor((int)u0, 32);
        unsigned x1 = (unsigned)__shfl_xor((int)u1, 32);
        unsigned x2 = (unsigned)__shfl_xor((int)u2, 32);
        unsigned x3 = (unsigned)__shfl_xor((int)u3, 32);
        BW f0, f1;
        f0.u[0] = hi ? x0 : wd[0];
        f0.u[1] = hi ? x1 : wd[1];
        f0.u[2] = hi ? wd[2] : x0;
        f0.u[3] = hi ? wd[3] : x1;
        f1.u[0] = hi ? x2 : wd[4];
        f1.u[1] = hi ? x3 : wd[5];
        f1.u[2] = hi ? wd[6] : x2;
        f1.u[3] = hi ? wd[7] : x3;
        __builtin_amdgcn_s_setprio(1);
        #pragma unroll
        for (int cc = 0; cc < 2; ++cc) {
          const BW& fr = cc ? f1 : f0;
          #pragma unroll
          for (int db = 0; db < 4; ++db) {
            bf16x8 vf = *(const bf16x8*)(vbase + db * 4096 +
                                         ((t2 * 64 + cc * 32 + hi16) ^ kswv));
            o[db] = __builtin_amdgcn_mfma_f32_32x32x16_bf16(vf, fr.v, o[db], 0, 0, 0);
          }
        }
        __builtin_amdgcn_s_setprio(0);
      }
    }

    __syncthreads();  // all PV(t) reads of Vs complete
    if (t + 1 < nt) {
      *(s16x8*)((char*)Vs + vXs[0]) = vr0;
      *(s16x8*)((char*)Vs + vXs[1]) = vr1;
      *(s16x8*)((char*)Vs + vXs[2]) = vr2;
      *(s16x8*)((char*)Vs + vXs[3]) = vr3;
    }
    __syncthreads();  // publishes V(t+1); drains K(t+1) gload_lds (vmcnt 0)
  }

  float invl = 1.0f / l_;
  const long aorow = ((long)(b * 2048 + q_abs)) * 4096 + h * 128 + hi * 4;
  #pragma unroll
  for (int db = 0; db < 4; ++db)
    #pragma unroll
    for (int r = 0; r < 16; ++r) {
      int doff = db * 32 + (r & 3) + 8 * (r >> 2);
      ao[aorow + doff] = f2bf(o[db][r] * invl);
    }
}

// ---------------- launcher --------------------------------------------------
extern "C" void kernel_launch(void* const* d_in, const int* in_sizes, int n_in,
                              void* d_out, int out_size, void* d_ws, size_t ws_size,
                              hipStream_t stream) {
  const float* x  = (const float*)d_in[0];
  const float* wq = (const float*)d_in[1];
  const float* wk = (const float*)d_in[2];
  const float* wv = (const float*)d_in[3];
  const float* wo = (const float*)d_in[4];
  float* out = (float*)d_out;

  char* ws = (char*)d_ws;
  short* xb    = (short*)(ws);               // x bf16; later reused as attn_out
  short* wqkvb = (short*)(ws + 33554432);    // wq|wk|wv bf16 (6144x4096)
  short* wob   = (short*)(ws + 83886080);
  short* qb    = (short*)(ws + 117440512);   // (B,H,S,D) post-RoPE
  short* kb    = (short*)(ws + 150994944);   // (B,Hkv,S,D) post-RoPE
  short* vb    = (short*)(ws + 159383552);   // (B,Hkv,D,S)  TRANSPOSED
  short* ao    = xb;

  float* nk = out + 16777216;  // new_k fp32 (B,Hkv,S,D) PRE-rope
  float* nv = out + 20971520;  // new_v fp32

  cast_all<<<28672, 256, 0, stream>>>(x, wq, wk, wv, wo, xb, wqkvb, wob);

  gemm_q<<<256, 512, 0, stream>>>(xb, wqkvb, qb);
  gemm_kv<<<256, 512, 0, stream>>>(xb, wqkvb + 16777216, kb, vb, nk, nv);
  flash_kernel<<<1024, 256, 0, stream>>>(qb, kb, vb, ao);
  gemm_out<<<256, 512, 0, stream>>>(ao, wob, out);
}

// Round 15
// 540.313 us; speedup vs baseline: 1.0248x; 1.0248x over previous
//
#include <hip/hip_runtime.h>
#include <hip/hip_bf16.h>

typedef __attribute__((ext_vector_type(8)))  short   s16x8;
typedef __attribute__((ext_vector_type(8)))  __bf16  bf16x8;
typedef __attribute__((ext_vector_type(4)))  float   f32x4;
typedef __attribute__((ext_vector_type(16))) float   f32x16;

#define DEV static __device__ __forceinline__

DEV short f2bf(float f) {
  unsigned u = __builtin_bit_cast(unsigned, f);
  u = (u + 0x7fff + ((u >> 16) & 1)) >> 16;
  return (short)u;
}
DEV float bf2f(short s) {
  unsigned u = ((unsigned)(unsigned short)s) << 16;
  return __builtin_bit_cast(float, u);
}

DEV void gload16(const void* g, void* l) {
  __builtin_amdgcn_global_load_lds(
      (const __attribute__((address_space(1))) unsigned int*)g,
      (__attribute__((address_space(3))) unsigned int*)l, 16, 0, 0);
}

DEV unsigned cvtpk(float lo, float hi) {
  unsigned r;
  asm("v_cvt_pk_bf16_f32 %0, %1, %2" : "=v"(r) : "v"(lo), "v"(hi));
  return r;
}

typedef union { unsigned u[4]; bf16x8 v; } BW;

// ---------------- fused cast fp32 -> bf16 for all 5 inputs ------------------
__global__ __launch_bounds__(256) void cast_all(
    const float* __restrict__ x,  const float* __restrict__ wq,
    const float* __restrict__ wk, const float* __restrict__ wv,
    const float* __restrict__ wo,
    short* __restrict__ xb, short* __restrict__ wqkvb, short* __restrict__ wob) {
  long i = (long)blockIdx.x * 256 + threadIdx.x;  // vector index
  const float* src;
  short* dst;
  long off;
  if (i < 2097152)       { src = x;  dst = xb;               off = i; }
  else if (i < 4194304)  { src = wq; dst = wqkvb;            off = i - 2097152; }
  else if (i < 4718592)  { src = wk; dst = wqkvb + 16777216; off = i - 4194304; }
  else if (i < 5242880)  { src = wv; dst = wqkvb + 20971520; off = i - 4718592; }
  else                   { src = wo; dst = wob;              off = i - 5242880; }
  long e = off * 8;
  float4 a = *(const float4*)(src + e);
  float4 b = *(const float4*)(src + e + 4);
  s16x8 o;
  o[0] = f2bf(a.x); o[1] = f2bf(a.y); o[2] = f2bf(a.z); o[3] = f2bf(a.w);
  o[4] = f2bf(b.x); o[5] = f2bf(b.y); o[6] = f2bf(b.z); o[7] = f2bf(b.w);
  *(s16x8*)(dst + e) = o;
}

// ---------------- GEMM-Q: 256x256 8-phase (proven), q + RoPE epilogue -------
__global__ __launch_bounds__(512, 2) void gemm_q(
    const short* __restrict__ A, const short* __restrict__ W,
    short* __restrict__ qb)
{
  __shared__ __align__(16) short lds[2][2][16384];  // [buf][0=A,1=B]

  const int tid = threadIdx.x;
  const int lane = tid & 63;
  const int w = tid >> 6;
  const int wm = w >> 2, wn = w & 3;          // 2M x 4N waves
  const int l15 = lane & 15, lg = lane >> 4;
  const int swz = (l15 & 7) << 4;

  int c = blockIdx.x & 7, j = blockIdx.x >> 3;
  const int tm = (c >> 2) * 8 + (j & 7);
  const int tn = (c & 3) * 4 + (j >> 3);

  const char* Ac = (const char*)A;
  const char* Wc = (const char*)W;

  int qXo[4];
  long aQ[4], bQ[4];
  #pragma unroll
  for (int q = 0; q < 4; ++q) {
    int X = q * 8192 + tid * 16;
    int row = X >> 7;
    int colS = (X & 127) ^ ((row & 7) << 4);
    qXo[q] = X;
    aQ[q] = (long)(tm * 256 + row) * 8192 + colS;
    bQ[q] = (long)(tn * 256 + row) * 8192 + colS;
  }

#define SA(TT, BB, Q)                                                        \
  if ((TT) < 64) gload16(Ac + aQ[Q] + (long)(TT) * 128,                      \
                         (char*)&lds[BB][0][0] + qXo[Q]);
#define SB(TT, BB, Q)                                                        \
  if ((TT) < 64) gload16(Wc + bQ[Q] + (long)(TT) * 128,                      \
                         (char*)&lds[BB][1][0] + qXo[Q]);

  f32x4 zero = {0.f, 0.f, 0.f, 0.f};
  f32x4 acc[8][4];
  #pragma unroll
  for (int i = 0; i < 8; ++i)
    #pragma unroll
    for (int jj = 0; jj < 4; ++jj) acc[i][jj] = zero;

  const int aro = (wm * 128 + l15) * 128;
  const int bro = (wn * 64 + l15) * 128;
  const int cs0 = (lg << 4) ^ swz;
  const int cs1 = (64 | (lg << 4)) ^ swz;

  SB(0, 0, 0) SB(0, 0, 1) SB(0, 0, 2) SB(0, 0, 3)
  SA(0, 0, 0) SA(0, 0, 1) SA(0, 0, 2) SA(0, 0, 3)
  asm volatile("s_waitcnt vmcnt(0)" ::: "memory");
  __builtin_amdgcn_s_barrier();

  #pragma clang loop unroll(disable)
  for (int t = 0; t < 64; ++t) {
    const int bt = t & 1, nb = bt ^ 1;
    const char* LA = (const char*)&lds[bt][0][0];
    const char* LB = (const char*)&lds[bt][1][0];
    bf16x8 af[4][2], bf0[2][2], bf1[2][2];

    // ---- phase 0 ----
    #pragma unroll
    for (int i = 0; i < 4; ++i) {
      af[i][0] = *(const bf16x8*)(LA + aro + i * 2048 + cs0);
      af[i][1] = *(const bf16x8*)(LA + aro + i * 2048 + cs1);
    }
    #pragma unroll
    for (int jj = 0; jj < 2; ++jj) {
      bf0[jj][0] = *(const bf16x8*)(LB + bro + jj * 2048 + cs0);
      bf0[jj][1] = *(const bf16x8*)(LB + bro + jj * 2048 + cs1);
    }
    SB(t + 1, nb, 0) SB(t + 1, nb, 1) SA(t + 1, nb, 0) SA(t + 1, nb, 2)
    __builtin_amdgcn_s_barrier();
    asm volatile("s_waitcnt lgkmcnt(0)" ::: "memory");
    __builtin_amdgcn_sched_barrier(0);
    __builtin_amdgcn_s_setprio(1);
    #pragma unroll
    for (int i = 0; i < 4; ++i)
      #pragma unroll
      for (int jj = 0; jj < 2; ++jj) {
        acc[i][jj] = __builtin_amdgcn_mfma_f32_16x16x32_bf16(af[i][0], bf0[jj][0], acc[i][jj], 0, 0, 0);
        acc[i][jj] = __builtin_amdgcn_mfma_f32_16x16x32_bf16(af[i][1], bf0[jj][1], acc[i][jj], 0, 0, 0);
      }
    __builtin_amdgcn_s_setprio(0);
    __builtin_amdgcn_s_barrier();

    // ---- phase 1 ----
    #pragma unroll
    for (int jj = 0; jj < 2; ++jj) {
      bf1[jj][0] = *(const bf16x8*)(LB + bro + (2 + jj) * 2048 + cs0);
      bf1[jj][1] = *(const bf16x8*)(LB + bro + (2 + jj) * 2048 + cs1);
    }
    SB(t + 1, nb, 2) SB(t + 1, nb, 3) SA(t + 1, nb, 1) SA(t + 1, nb, 3)
    __builtin_amdgcn_s_barrier();
    asm volatile("s_waitcnt lgkmcnt(0)" ::: "memory");
    __builtin_amdgcn_sched_barrier(0);
    __builtin_amdgcn_s_setprio(1);
    #pragma unroll
    for (int i = 0; i < 4; ++i)
      #pragma unroll
      for (int jj = 0; jj < 2; ++jj) {
        acc[i][2 + jj] = __builtin_amdgcn_mfma_f32_16x16x32_bf16(af[i][0], bf1[jj][0], acc[i][2 + jj], 0, 0, 0);
        acc[i][2 + jj] = __builtin_amdgcn_mfma_f32_16x16x32_bf16(af[i][1], bf1[jj][1], acc[i][2 + jj], 0, 0, 0);
      }
    __builtin_amdgcn_s_setprio(0);
    if (t == 63) {
      asm volatile("s_waitcnt vmcnt(0)" ::: "memory");
    } else {
      asm volatile("s_waitcnt vmcnt(8)" ::: "memory");
    }
    __builtin_amdgcn_sched_barrier(0);
    __builtin_amdgcn_s_barrier();

    // ---- phase 2 ----
    #pragma unroll
    for (int i = 0; i < 4; ++i) {
      af[i][0] = *(const bf16x8*)(LA + aro + (4 + i) * 2048 + cs0);
      af[i][1] = *(const bf16x8*)(LA + aro + (4 + i) * 2048 + cs1);
    }
    __builtin_amdgcn_s_barrier();
    asm volatile("s_waitcnt lgkmcnt(0)" ::: "memory");
    __builtin_amdgcn_sched_barrier(0);
    __builtin_amdgcn_s_setprio(1);
    #pragma unroll
    for (int i = 0; i < 4; ++i)
      #pragma unroll
      for (int jj = 0; jj < 2; ++jj) {
        acc[4 + i][jj] = __builtin_amdgcn_mfma_f32_16x16x32_bf16(af[i][0], bf0[jj][0], acc[4 + i][jj], 0, 0, 0);
        acc[4 + i][jj] = __builtin_amdgcn_mfma_f32_16x16x32_bf16(af[i][1], bf0[jj][1], acc[4 + i][jj], 0, 0, 0);
      }
    __builtin_amdgcn_s_setprio(0);
    __builtin_amdgcn_s_barrier();

    // ---- phase 3 ----
    __builtin_amdgcn_s_setprio(1);
    #pragma unroll
    for (int i = 0; i < 4; ++i)
      #pragma unroll
      for (int jj = 0; jj < 2; ++jj) {
        acc[4 + i][2 + jj] = __builtin_amdgcn_mfma_f32_16x16x32_bf16(af[i][0], bf1[jj][0], acc[4 + i][2 + jj], 0, 0, 0);
        acc[4 + i][2 + jj] = __builtin_amdgcn_mfma_f32_16x16x32_bf16(af[i][1], bf1[jj][1], acc[4 + i][2 + jj], 0, 0, 0);
      }
    __builtin_amdgcn_s_setprio(0);
    if (t < 63) {
      asm volatile("s_waitcnt vmcnt(2)" ::: "memory");
      __builtin_amdgcn_sched_barrier(0);
      __builtin_amdgcn_s_barrier();
    }
  }
#undef SA
#undef SB

  // epilogue: all columns are q -> RoPE (pair = adjacent l15 lane) + write qb
  #pragma unroll
  for (int mr = 0; mr < 8; ++mr) {
    int mbase = tm * 256 + wm * 128 + mr * 16 + lg * 4;
    #pragma unroll
    for (int nr = 0; nr < 4; ++nr) {
      int col = tn * 256 + wn * 64 + nr * 16 + l15;
      float pv[4];
      #pragma unroll
      for (int r = 0; r < 4; ++r) pv[r] = __shfl_xor(acc[mr][nr][r], 1);
      #pragma unroll
      for (int r = 0; r < 4; ++r) {
        int m = mbase + r;
        float v = acc[mr][nr][r];
        int b = m >> 11, s = m & 2047;
        int h = col >> 7, d = col & 127;
        float x1 = (l15 & 1) ? pv[r] : v;
        float x2 = (l15 & 1) ? v : pv[r];
        float inv = __expf(-0.14391157f * (float)(d >> 1));  // 1e4^(-2j/128)
        float sn, cs;
        __sincosf((float)s * inv, &sn, &cs);
        float rr = (l15 & 1) ? (x1 * sn + x2 * cs) : (x1 * cs - x2 * sn);
        qb[((long)((b * 32 + h) * 2048 + s)) * 128 + d] = f2bf(rr);
      }
    }
  }
}

// ---------------- GEMM-KV: 256x128, BK=64, 3-buffer (proven), N=2048 --------
__global__ __launch_bounds__(512, 2) void gemm_kv(
    const short* __restrict__ A, const short* __restrict__ W,
    short* __restrict__ kb, short* __restrict__ vb,
    float* __restrict__ nk, float* __restrict__ nv)
{
  __shared__ short lds[3][24576];  // 3 x 48KB: A at +0 (32KB), B at +32768

  const int tid = threadIdx.x;
  const int lane = tid & 63;
  const int w = tid >> 6;
  const int wm = w >> 1, wn = w & 1;          // 4 x 2 waves
  const int l15 = lane & 15, lg = lane >> 4;
  const int swz = (l15 & 7) << 4;

  int c = blockIdx.x & 7, j = blockIdx.x >> 3;
  const int tm = (c >> 2) * 8 + (j & 7);
  const int tn = (c & 3) * 4 + (j >> 3);     // 16 tn tiles of 128

  const char* Ac = (const char*)A;
  const char* Wc = (const char*)W;

  int aXo[4], bXo[2];
  long aSrc[4], bSrc[2];
  #pragma unroll
  for (int l4 = 0; l4 < 4; ++l4) {
    int X = tid * 16 + l4 * 8192;
    int row = X >> 7;
    int colS = (X & 127) ^ (((X >> 7) & 7) << 4);
    aXo[l4] = X;
    aSrc[l4] = (long)(tm * 256 + row) * 8192 + colS;
  }
  #pragma unroll
  for (int l4 = 0; l4 < 2; ++l4) {
    int X = tid * 16 + l4 * 8192;
    int row = X >> 7;
    int colS = (X & 127) ^ (((X >> 7) & 7) << 4);
    bXo[l4] = X;
    bSrc[l4] = (long)(tn * 128 + row) * 8192 + colS;
  }

#define STAGE(TT, BI)                                                        \
  {                                                                          \
    const long kof_ = (long)(TT) * 128;                                      \
    _Pragma("unroll")                                                        \
    for (int l4 = 0; l4 < 4; ++l4)                                           \
      gload16(Ac + aSrc[l4] + kof_, (char*)&lds[BI][0] + aXo[l4]);           \
    _Pragma("unroll")                                                        \
    for (int l4 = 0; l4 < 2; ++l4)                                           \
      gload16(Wc + bSrc[l4] + kof_, (char*)&lds[BI][0] + 32768 + bXo[l4]);   \
  }

  f32x4 zero = {0.f, 0.f, 0.f, 0.f};
  f32x4 acc[4][4];
  #pragma unroll
  for (int i = 0; i < 4; ++i)
    #pragma unroll
    for (int jj = 0; jj < 4; ++jj) acc[i][jj] = zero;

  const int aro = (wm * 64 + l15) * 128;
  const int bro = 32768 + (wn * 64 + l15) * 128;
  const int cs0 = (lg << 4) ^ swz;
  const int cs1 = (64 | (lg << 4)) ^ swz;

#define MF(a0, a1, MR)                                                       \
  __builtin_amdgcn_s_setprio(1);                                             \
  _Pragma("unroll")                                                          \
  for (int nr = 0; nr < 4; ++nr) {                                           \
    acc[MR][nr] = __builtin_amdgcn_mfma_f32_16x16x32_bf16(                   \
        a0, bfr[nr][0], acc[MR][nr], 0, 0, 0);                               \
    acc[MR][nr] = __builtin_amdgcn_mfma_f32_16x16x32_bf16(                   \
        a1, bfr[nr][1], acc[MR][nr], 0, 0, 0);                               \
  }                                                                          \
  __builtin_amdgcn_s_setprio(0);

#define TILE(T, BI)                                                          \
  {                                                                          \
    const char* L = (const char*)&lds[BI][0];                                \
    bf16x8 bfr[4][2];                                                        \
    _Pragma("unroll")                                                        \
    for (int nr = 0; nr < 4; ++nr) {                                         \
      bfr[nr][0] = *(const bf16x8*)(L + bro + nr * 2048 + cs0);              \
      bfr[nr][1] = *(const bf16x8*)(L + bro + nr * 2048 + cs1);              \
    }                                                                        \
    bf16x8 g0, g1, h0, h1;                                                   \
    g0 = *(const bf16x8*)(L + aro + 0 * 2048 + cs0);                         \
    g1 = *(const bf16x8*)(L + aro + 0 * 2048 + cs1);                         \
    h0 = *(const bf16x8*)(L + aro + 1 * 2048 + cs0);                         \
    h1 = *(const bf16x8*)(L + aro + 1 * 2048 + cs1);                         \
    asm volatile("s_waitcnt lgkmcnt(2)" ::: "memory");                       \
    __builtin_amdgcn_sched_barrier(0);                                       \
    MF(g0, g1, 0)                                                            \
    g0 = *(const bf16x8*)(L + aro + 2 * 2048 + cs0);                         \
    g1 = *(const bf16x8*)(L + aro + 2 * 2048 + cs1);                         \
    asm volatile("s_waitcnt lgkmcnt(2)" ::: "memory");                       \
    __builtin_amdgcn_sched_barrier(0);                                       \
    MF(h0, h1, 1)                                                            \
    h0 = *(const bf16x8*)(L + aro + 3 * 2048 + cs0);                         \
    h1 = *(const bf16x8*)(L + aro + 3 * 2048 + cs1);                         \
    asm volatile("s_waitcnt lgkmcnt(2)" ::: "memory");                       \
    __builtin_amdgcn_sched_barrier(0);                                       \
    MF(g0, g1, 2)                                                            \
    asm volatile("s_waitcnt lgkmcnt(0)" ::: "memory");                       \
    __builtin_amdgcn_sched_barrier(0);                                       \
    MF(h0, h1, 3)                                                            \
    if ((T) < 62) {                                                          \
      asm volatile("s_waitcnt vmcnt(6)" ::: "memory");                       \
    } else if ((T) == 62) {                                                  \
      asm volatile("s_waitcnt vmcnt(0)" ::: "memory");                       \
    }                                                                        \
    if ((T) < 63) __builtin_amdgcn_s_barrier();                              \
    if ((T) < 61) { STAGE((T) + 3, BI) }                                     \
  }

  STAGE(0, 0)
  STAGE(1, 1)
  STAGE(2, 2)
  asm volatile("s_waitcnt vmcnt(12)" ::: "memory");
  __builtin_amdgcn_s_barrier();

  #pragma clang loop unroll(disable)
  for (int t3 = 0; t3 < 63; t3 += 3) {
    TILE(t3 + 0, 0)
    TILE(t3 + 1, 1)
    TILE(t3 + 2, 2)
  }
  TILE(63, 0)

#undef STAGE
#undef TILE
#undef MF

  // epilogue: col 0..1023 = k (RoPE + nk), 1024..2047 = v (nv + vb^T)
  #pragma unroll
  for (int mr = 0; mr < 4; ++mr) {
    int mbase = tm * 256 + wm * 64 + mr * 16 + lg * 4;
    #pragma unroll
    for (int nr = 0; nr < 4; ++nr) {
      int col = tn * 128 + wn * 64 + nr * 16 + l15;
      float pv[4];
      #pragma unroll
      for (int r = 0; r < 4; ++r) pv[r] = __shfl_xor(acc[mr][nr][r], 1);
      #pragma unroll
      for (int r = 0; r < 4; ++r) {
        int m = mbase + r;
        float v = acc[mr][nr][r];
        int b = m >> 11, s = m & 2047;
        if (col < 1024) {  // k: RoPE
          int h = col >> 7, d = col & 127;
          float x1 = (l15 & 1) ? pv[r] : v;
          float x2 = (l15 & 1) ? v : pv[r];
          float inv = __expf(-0.14391157f * (float)(d >> 1));
          float sn, cs;
          __sincosf((float)s * inv, &sn, &cs);
          float rr = (l15 & 1) ? (x1 * sn + x2 * cs) : (x1 * cs - x2 * sn);
          long o = ((long)((b * 8 + h) * 2048 + s)) * 128 + d;
          kb[o] = f2bf(rr);
          nk[o] = v;  // PRE-rope
        } else {
          int c2 = col - 1024;
          int h = c2 >> 7, d = c2 & 127;
          long o = ((long)((b * 8 + h) * 2048 + s)) * 128 + d;
          nv[o] = v;
          vb[((long)((b * 8 + h) * 128 + d)) * 2048 + s] = f2bf(v);  // [b][hkv][d][s]
        }
      }
    }
  }
}

// ---------------- GEMM2: out-proj. 256x256, 8-phase (proven) ----------------
__global__ __launch_bounds__(512, 2) void gemm_out(
    const short* __restrict__ A, const short* __restrict__ W,
    float* __restrict__ Cout)
{
  __shared__ __align__(16) short lds[2][2][16384];  // [buf][0=A,1=B]

  const int tid = threadIdx.x;
  const int lane = tid & 63;
  const int w = tid >> 6;
  const int wm = w >> 2, wn = w & 3;
  const int l15 = lane & 15, lg = lane >> 4;
  const int swz = (l15 & 7) << 4;

  int c = blockIdx.x & 7, j = blockIdx.x >> 3;
  const int tm = (c >> 2) * 8 + (j & 7);
  const int tn = (c & 3) * 4 + (j >> 3);

  const char* Ac = (const char*)A;
  const char* Wc = (const char*)W;

  int qXo[4];
  long aQ[4], bQ[4];
  #pragma unroll
  for (int q = 0; q < 4; ++q) {
    int X = q * 8192 + tid * 16;
    int row = X >> 7;
    int colS = (X & 127) ^ ((row & 7) << 4);
    qXo[q] = X;
    aQ[q] = (long)(tm * 256 + row) * 8192 + colS;
    bQ[q] = (long)(tn * 256 + row) * 8192 + colS;
  }

#define SA(TT, BB, Q)                                                        \
  if ((TT) < 64) gload16(Ac + aQ[Q] + (long)(TT) * 128,                      \
                         (char*)&lds[BB][0][0] + qXo[Q]);
#define SB(TT, BB, Q)                                                        \
  if ((TT) < 64) gload16(Wc + bQ[Q] + (long)(TT) * 128,                      \
                         (char*)&lds[BB][1][0] + qXo[Q]);

  f32x4 zero = {0.f, 0.f, 0.f, 0.f};
  f32x4 acc[8][4];
  #pragma unroll
  for (int i = 0; i < 8; ++i)
    #pragma unroll
    for (int jj = 0; jj < 4; ++jj) acc[i][jj] = zero;

  const int aro = (wm * 128 + l15) * 128;
  const int bro = (wn * 64 + l15) * 128;
  const int cs0 = (lg << 4) ^ swz;
  const int cs1 = (64 | (lg << 4)) ^ swz;

  SB(0, 0, 0) SB(0, 0, 1) SB(0, 0, 2) SB(0, 0, 3)
  SA(0, 0, 0) SA(0, 0, 1) SA(0, 0, 2) SA(0, 0, 3)
  asm volatile("s_waitcnt vmcnt(0)" ::: "memory");
  __builtin_amdgcn_s_barrier();

  #pragma clang loop unroll(disable)
  for (int t = 0; t < 64; ++t) {
    const int bt = t & 1, nb = bt ^ 1;
    const char* LA = (const char*)&lds[bt][0][0];
    const char* LB = (const char*)&lds[bt][1][0];
    bf16x8 af[4][2], bf0[2][2], bf1[2][2];

    #pragma unroll
    for (int i = 0; i < 4; ++i) {
      af[i][0] = *(const bf16x8*)(LA + aro + i * 2048 + cs0);
      af[i][1] = *(const bf16x8*)(LA + aro + i * 2048 + cs1);
    }
    #pragma unroll
    for (int jj = 0; jj < 2; ++jj) {
      bf0[jj][0] = *(const bf16x8*)(LB + bro + jj * 2048 + cs0);
      bf0[jj][1] = *(const bf16x8*)(LB + bro + jj * 2048 + cs1);
    }
    SB(t + 1, nb, 0) SB(t + 1, nb, 1) SA(t + 1, nb, 0) SA(t + 1, nb, 2)
    __builtin_amdgcn_s_barrier();
    asm volatile("s_waitcnt lgkmcnt(0)" ::: "memory");
    __builtin_amdgcn_sched_barrier(0);
    __builtin_amdgcn_s_setprio(1);
    #pragma unroll
    for (int i = 0; i < 4; ++i)
      #pragma unroll
      for (int jj = 0; jj < 2; ++jj) {
        acc[i][jj] = __builtin_amdgcn_mfma_f32_16x16x32_bf16(af[i][0], bf0[jj][0], acc[i][jj], 0, 0, 0);
        acc[i][jj] = __builtin_amdgcn_mfma_f32_16x16x32_bf16(af[i][1], bf0[jj][1], acc[i][jj], 0, 0, 0);
      }
    __builtin_amdgcn_s_setprio(0);
    __builtin_amdgcn_s_barrier();

    #pragma unroll
    for (int jj = 0; jj < 2; ++jj) {
      bf1[jj][0] = *(const bf16x8*)(LB + bro + (2 + jj) * 2048 + cs0);
      bf1[jj][1] = *(const bf16x8*)(LB + bro + (2 + jj) * 2048 + cs1);
    }
    SB(t + 1, nb, 2) SB(t + 1, nb, 3) SA(t + 1, nb, 1) SA(t + 1, nb, 3)
    __builtin_amdgcn_s_barrier();
    asm volatile("s_waitcnt lgkmcnt(0)" ::: "memory");
    __builtin_amdgcn_sched_barrier(0);
    __builtin_amdgcn_s_setprio(1);
    #pragma unroll
    for (int i = 0; i < 4; ++i)
      #pragma unroll
      for (int jj = 0; jj < 2; ++jj) {
        acc[i][2 + jj] = __builtin_amdgcn_mfma_f32_16x16x32_bf16(af[i][0], bf1[jj][0], acc[i][2 + jj], 0, 0, 0);
        acc[i][2 + jj] = __builtin_amdgcn_mfma_f32_16x16x32_bf16(af[i][1], bf1[jj][1], acc[i][2 + jj], 0, 0, 0);
      }
    __builtin_amdgcn_s_setprio(0);
    if (t == 63) {
      asm volatile("s_waitcnt vmcnt(0)" ::: "memory");
    } else {
      asm volatile("s_waitcnt vmcnt(8)" ::: "memory");
    }
    __builtin_amdgcn_sched_barrier(0);
    __builtin_amdgcn_s_barrier();

    #pragma unroll
    for (int i = 0; i < 4; ++i) {
      af[i][0] = *(const bf16x8*)(LA + aro + (4 + i) * 2048 + cs0);
      af[i][1] = *(const bf16x8*)(LA + aro + (4 + i) * 2048 + cs1);
    }
    __builtin_amdgcn_s_barrier();
    asm volatile("s_waitcnt lgkmcnt(0)" ::: "memory");
    __builtin_amdgcn_sched_barrier(0);
    __builtin_amdgcn_s_setprio(1);
    #pragma unroll
    for (int i = 0; i < 4; ++i)
      #pragma unroll
      for (int jj = 0; jj < 2; ++jj) {
        acc[4 + i][jj] = __builtin_amdgcn_mfma_f32_16x16x32_bf16(af[i][0], bf0[jj][0], acc[4 + i][jj], 0, 0, 0);
        acc[4 + i][jj] = __builtin_amdgcn_mfma_f32_16x16x32_bf16(af[i][1], bf0[jj][1], acc[4 + i][jj], 0, 0, 0);
      }
    __builtin_amdgcn_s_setprio(0);
    __builtin_amdgcn_s_barrier();

    __builtin_amdgcn_s_setprio(1);
    #pragma unroll
    for (int i = 0; i < 4; ++i)
      #pragma unroll
      for (int jj = 0; jj < 2; ++jj) {
        acc[4 + i][2 + jj] = __builtin_amdgcn_mfma_f32_16x16x32_bf16(af[i][0], bf1[jj][0], acc[4 + i][2 + jj], 0, 0, 0);
        acc[4 + i][2 + jj] = __builtin_amdgcn_mfma_f32_16x16x32_bf16(af[i][1], bf1[jj][1], acc[4 + i][2 + jj], 0, 0, 0);
      }
    __builtin_amdgcn_s_setprio(0);
    if (t < 63) {
      asm volatile("s_waitcnt vmcnt(2)" ::: "memory");
      __builtin_amdgcn_sched_barrier(0);
      __builtin_amdgcn_s_barrier();
    }
  }
#undef SA
#undef SB

  #pragma unroll
  for (int mr = 0; mr < 8; ++mr) {
    int mbase = tm * 256 + wm * 128 + mr * 16 + lg * 4;
    #pragma unroll
    for (int nr = 0; nr < 4; ++nr) {
      int col = tn * 256 + wn * 64 + nr * 16 + l15;
      #pragma unroll
      for (int r = 0; r < 4; ++r)
        Cout[(long)(mbase + r) * 4096 + col] = acc[mr][nr][r];
    }
  }
}

// ---------------- Flash attention v7: R13 structure + 16-spread K swizzle ---
// grid 1024, 256 thr = 4 waves; Q tile 128, wave 32 q rows, KV = 64.
// K/V double-buffered via gload_lds (pre-swizzled source); 1 barrier/iter.
// K swizzle (row&15)<<4 (rows 256B -> legal): QK 4-way -> 2-way conflicts.
// Tree-shaped max/sum reductions (depth 4) cut softmax dependency chains.
__global__ __launch_bounds__(256) void flash_kernel(
    const short* __restrict__ qb, const short* __restrict__ kb,
    const short* __restrict__ vt, short* __restrict__ ao)
{
  const int bid = blockIdx.x;
  const int qt = 15 - (bid >> 6);   // LPT: heaviest blocks dispatch first
  const int hb = bid & 63;
  const int h = hb & 31, b = hb >> 5;
  const int hkv = h >> 2;
  const int tid = threadIdx.x, w = tid >> 6, lane = tid & 63;
  const int l31 = lane & 31, hi = lane >> 5;
  const int hi16 = hi * 16;
  const int q0 = qt * 128 + w * 32;
  const int q_abs = q0 + l31;

  const short* Q  = qb + (long)(b * 32 + h) * 2048 * 128;
  const char*  Kg = (const char*)(kb + (long)(b * 8 + hkv) * 2048 * 128);
  const char*  Vg = (const char*)(vt + (long)(b * 8 + hkv) * 2048 * 128);  // [d][s]

  __shared__ short Ks[2][64 * 128];  // [kv][d], 16B chunks XOR-swizzled (kv&15)
  __shared__ short Vs[2][128 * 64];  // [d][kv], 16B chunks XOR-swizzled (d&7)

  int skX[4], svRow[4], svCol[4], Xo[4];
  #pragma unroll
  for (int i2 = 0; i2 < 4; ++i2) {
    int X = tid * 16 + i2 * 4096;
    Xo[i2] = X;
    skX[i2] = X ^ (((X >> 8) & 15) << 4);
    int sv = X ^ (((X >> 7) & 7) << 4);
    svRow[i2] = sv >> 7;
    svCol[i2] = sv & 127;
  }

  bf16x8 qf[8];
  #pragma unroll
  for (int c = 0; c < 8; ++c)
    qf[c] = *(const bf16x8*)&Q[(long)q_abs * 128 + c * 16 + hi * 8];

  f32x16 o[4];
  #pragma unroll
  for (int db = 0; db < 4; ++db)
    #pragma unroll
    for (int r = 0; r < 16; ++r) o[db][r] = 0.f;
  float m_ = -3e38f, l_ = 0.f;

  const float scale2 = 0.08838834764831845f * 1.4426950408889634f;
  const int nt = 2 * (qt + 1);
  const int kswk = (l31 & 15) << 4;
  const int kswv = (l31 & 7) << 4;

  #pragma unroll
  for (int i2 = 0; i2 < 4; ++i2) {
    gload16(Kg + skX[i2], (char*)Ks[0] + Xo[i2]);
    gload16(Vg + ((long)svRow[i2] * 4096 + svCol[i2]), (char*)Vs[0] + Xo[i2]);
  }

  for (int t = 0; t < nt; ++t) {
    const int kv0 = t * 64;
    const int cur = t & 1;
    __syncthreads();
    if (t + 1 < nt) {
      const long kvb = (long)(kv0 + 64);
      #pragma unroll
      for (int i2 = 0; i2 < 4; ++i2) {
        gload16(Kg + kvb * 256 + skX[i2], (char*)Ks[cur ^ 1] + Xo[i2]);
        gload16(Vg + ((long)svRow[i2] * 4096 + kvb * 2 + svCol[i2]),
                (char*)Vs[cur ^ 1] + Xo[i2]);
      }
    }
    if (kv0 > q0 + 31) continue;

    f32x16 s0, s1;
    #pragma unroll
    for (int r = 0; r < 16; ++r) { s0[r] = 0.f; s1[r] = 0.f; }
    const char* kbase = (const char*)Ks[cur] + l31 * 256;
    __builtin_amdgcn_s_setprio(1);
    #pragma unroll
    for (int c = 0; c < 8; ++c) {
      bf16x8 kf0 = *(const bf16x8*)(kbase + ((c * 32 + hi16) ^ kswk));
      bf16x8 kf1 = *(const bf16x8*)(kbase + 8192 + ((c * 32 + hi16) ^ kswk));
      s0 = __builtin_amdgcn_mfma_f32_32x32x16_bf16(kf0, qf[c], s0, 0, 0, 0);
      s1 = __builtin_amdgcn_mfma_f32_32x32x16_bf16(kf1, qf[c], s1, 0, 0, 0);
    }
    __builtin_amdgcn_s_setprio(0);

    const bool diag = (kv0 + 63 > q0);
    if (diag) {
      #pragma unroll
      for (int r = 0; r < 16; ++r) {
        int krow = (r & 3) + 8 * (r >> 2) + 4 * hi;
        if (kv0 + krow > q_abs)      s0[r] = -3e38f;
        if (kv0 + 32 + krow > q_abs) s1[r] = -3e38f;
      }
    }
    // tree max (depth 4+1, cuts 31-deep dependent chain)
    float tm_[8];
    #pragma unroll
    for (int r = 0; r < 8; ++r)
      tm_[r] = fmaxf(fmaxf(s0[r], s0[r + 8]), fmaxf(s1[r], s1[r + 8]));
    #pragma unroll
    for (int st = 4; st >= 1; st >>= 1)
      #pragma unroll
      for (int r = 0; r < st; ++r) tm_[r] = fmaxf(tm_[r], tm_[r + st]);
    float mx = tm_[0] * scale2;
    mx = fmaxf(mx, __shfl_xor(mx, 32));
    int need = mx > m_ + 11.5f;
    if (__any(need)) {
      float mn = fmaxf(m_, mx);
      float fac = exp2f(m_ - mn);
      m_ = mn;
      l_ *= fac;
      #pragma unroll
      for (int db = 0; db < 4; ++db)
        #pragma unroll
        for (int r = 0; r < 16; ++r) o[db][r] *= fac;
    }
    // exp2 + tree sum
    float ts[8];
    #pragma unroll
    for (int r = 0; r < 16; ++r) {
      s0[r] = exp2f(fmaf(s0[r], scale2, -m_));
      s1[r] = exp2f(fmaf(s1[r], scale2, -m_));
    }
    #pragma unroll
    for (int r = 0; r < 8; ++r)
      ts[r] = (s0[r] + s0[r + 8]) + (s1[r] + s1[r + 8]);
    #pragma unroll
    for (int st = 4; st >= 1; st >>= 1)
      #pragma unroll
      for (int r = 0; r < st; ++r) ts[r] += ts[r + st];
    float rs = ts[0];
    rs += __shfl_xor(rs, 32);
    l_ += rs;

    const char* vbase = (const char*)Vs[cur] + l31 * 128;
    #pragma unroll
    for (int t2 = 0; t2 < 2; ++t2) {
      const f32x16 sp = t2 ? s1 : s0;
      unsigned wd[8];
      #pragma unroll
      for (int jj = 0; jj < 8; ++jj) wd[jj] = cvtpk(sp[2 * jj], sp[2 * jj + 1]);
      unsigned u0 = hi ? wd[0] : wd[2];
      unsigned u1 = hi ? wd[1] : wd[3];
      unsigned u2 = hi ? wd[4] : wd[6];
      unsigned u3 = hi ? wd[5] : wd[7];
      unsigned x0 = (unsigned)__shfl_xor((int)u0, 32);
      unsigned x1 = (unsigned)__shfl_xor((int)u1, 32);
      unsigned x2 = (unsigned)__shfl_xor((int)u2, 32);
      unsigned x3 = (unsigned)__shfl_xor((int)u3, 32);
      BW f0, f1;
      f0.u[0] = hi ? x0 : wd[0];
      f0.u[1] = hi ? x1 : wd[1];
      f0.u[2] = hi ? wd[2] : x0;
      f0.u[3] = hi ? wd[3] : x1;
      f1.u[0] = hi ? x2 : wd[4];
      f1.u[1] = hi ? x3 : wd[5];
      f1.u[2] = hi ? wd[6] : x2;
      f1.u[3] = hi ? wd[7] : x3;
      __builtin_amdgcn_s_setprio(1);
      #pragma unroll
      for (int cc = 0; cc < 2; ++cc) {
        const BW& fr = cc ? f1 : f0;
        #pragma unroll
        for (int db = 0; db < 4; ++db) {
          bf16x8 vf = *(const bf16x8*)(vbase + db * 4096 +
                                       ((t2 * 64 + cc * 32 + hi16) ^ kswv));
          o[db] = __builtin_amdgcn_mfma_f32_32x32x16_bf16(vf, fr.v, o[db], 0, 0, 0);
        }
      }
      __builtin_amdgcn_s_setprio(0);
    }
  }

  float invl = 1.0f / l_;
  const long aorow = ((long)(b * 2048 + q_abs)) * 4096 + h * 128 + hi * 4;
  #pragma unroll
  for (int db = 0; db < 4; ++db)
    #pragma unroll
    for (int r = 0; r < 16; ++r) {
      int doff = db * 32 + (r & 3) + 8 * (r >> 2);
      ao[aorow + doff] = f2bf(o[db][r] * invl);
    }
}

// ---------------- launcher --------------------------------------------------
extern "C" void kernel_launch(void* const* d_in, const int* in_sizes, int n_in,
                              void* d_out, int out_size, void* d_ws, size_t ws_size,
                              hipStream_t stream) {
  const float* x  = (const float*)d_in[0];
  const float* wq = (const float*)d_in[1];
  const float* wk = (const float*)d_in[2];
  const float* wv = (const float*)d_in[3];
  const float* wo = (const float*)d_in[4];
  float* out = (float*)d_out;

  char* ws = (char*)d_ws;
  short* xb    = (short*)(ws);               // x bf16; later reused as attn_out
  short* wqkvb = (short*)(ws + 33554432);    // wq|wk|wv bf16 (6144x4096)
  short* wob   = (short*)(ws + 83886080);
  short* qb    = (short*)(ws + 117440512);   // (B,H,S,D) post-RoPE
  short* kb    = (short*)(ws + 150994944);   // (B,Hkv,S,D) post-RoPE
  short* vb    = (short*)(ws + 159383552);   // (B,Hkv,D,S)  TRANSPOSED
  short* ao    = xb;

  float* nk = out + 16777216;  // new_k fp32 (B,Hkv,S,D) PRE-rope
  float* nv = out + 20971520;  // new_v fp32

  cast_all<<<28672, 256, 0, stream>>>(x, wq, wk, wv, wo, xb, wqkvb, wob);

  gemm_q<<<256, 512, 0, stream>>>(xb, wqkvb, qb);
  gemm_kv<<<256, 512, 0, stream>>>(xb, wqkvb + 16777216, kb, vb, nk, nv);
  flash_kernel<<<1024, 256, 0, stream>>>(qb, kb, vb, ao);
  gemm_out<<<256, 512, 0, stream>>>(ao, wob, out);
}

// Round 16
// 482.966 us; speedup vs baseline: 1.1465x; 1.1187x over previous
//
#include <hip/hip_runtime.h>
#include <hip/hip_bf16.h>

typedef __attribute__((ext_vector_type(8)))  short   s16x8;
typedef __attribute__((ext_vector_type(8)))  __bf16  bf16x8;
typedef __attribute__((ext_vector_type(4)))  float   f32x4;
typedef __attribute__((ext_vector_type(16))) float   f32x16;

#define DEV static __device__ __forceinline__

DEV short f2bf(float f) {
  unsigned u = __builtin_bit_cast(unsigned, f);
  u = (u + 0x7fff + ((u >> 16) & 1)) >> 16;
  return (short)u;
}
DEV float bf2f(short s) {
  unsigned u = ((unsigned)(unsigned short)s) << 16;
  return __builtin_bit_cast(float, u);
}

DEV void gload16(const void* g, void* l) {
  __builtin_amdgcn_global_load_lds(
      (const __attribute__((address_space(1))) unsigned int*)g,
      (__attribute__((address_space(3))) unsigned int*)l, 16, 0, 0);
}

DEV unsigned cvtpk(float lo, float hi) {
  unsigned r;
  asm("v_cvt_pk_bf16_f32 %0, %1, %2" : "=v"(r) : "v"(lo), "v"(hi));
  return r;
}

typedef union { unsigned u[4]; bf16x8 v; } BW;

// ---------------- fused cast fp32 -> bf16 for all 5 inputs ------------------
__global__ __launch_bounds__(256) void cast_all(
    const float* __restrict__ x,  const float* __restrict__ wq,
    const float* __restrict__ wk, const float* __restrict__ wv,
    const float* __restrict__ wo,
    short* __restrict__ xb, short* __restrict__ wqkvb, short* __restrict__ wob) {
  long i = (long)blockIdx.x * 256 + threadIdx.x;  // vector index
  const float* src;
  short* dst;
  long off;
  if (i < 2097152)       { src = x;  dst = xb;               off = i; }
  else if (i < 4194304)  { src = wq; dst = wqkvb;            off = i - 2097152; }
  else if (i < 4718592)  { src = wk; dst = wqkvb + 16777216; off = i - 4194304; }
  else if (i < 5242880)  { src = wv; dst = wqkvb + 20971520; off = i - 4718592; }
  else                   { src = wo; dst = wob;              off = i - 5242880; }
  long e = off * 8;
  float4 a = *(const float4*)(src + e);
  float4 b = *(const float4*)(src + e + 4);
  s16x8 o;
  o[0] = f2bf(a.x); o[1] = f2bf(a.y); o[2] = f2bf(a.z); o[3] = f2bf(a.w);
  o[4] = f2bf(b.x); o[5] = f2bf(b.y); o[6] = f2bf(b.z); o[7] = f2bf(b.w);
  *(s16x8*)(dst + e) = o;
}

// ---------------- GEMM-Q: 256x256 8-phase (proven), q + RoPE epilogue -------
__global__ __launch_bounds__(512, 2) void gemm_q(
    const short* __restrict__ A, const short* __restrict__ W,
    short* __restrict__ qb)
{
  __shared__ __align__(16) short lds[2][2][16384];  // [buf][0=A,1=B]

  const int tid = threadIdx.x;
  const int lane = tid & 63;
  const int w = tid >> 6;
  const int wm = w >> 2, wn = w & 3;          // 2M x 4N waves
  const int l15 = lane & 15, lg = lane >> 4;
  const int swz = (l15 & 7) << 4;

  int c = blockIdx.x & 7, j = blockIdx.x >> 3;
  const int tm = (c >> 2) * 8 + (j & 7);
  const int tn = (c & 3) * 4 + (j >> 3);

  const char* Ac = (const char*)A;
  const char* Wc = (const char*)W;

  int qXo[4];
  long aQ[4], bQ[4];
  #pragma unroll
  for (int q = 0; q < 4; ++q) {
    int X = q * 8192 + tid * 16;
    int row = X >> 7;
    int colS = (X & 127) ^ ((row & 7) << 4);
    qXo[q] = X;
    aQ[q] = (long)(tm * 256 + row) * 8192 + colS;
    bQ[q] = (long)(tn * 256 + row) * 8192 + colS;
  }

#define SA(TT, BB, Q)                                                        \
  if ((TT) < 64) gload16(Ac + aQ[Q] + (long)(TT) * 128,                      \
                         (char*)&lds[BB][0][0] + qXo[Q]);
#define SB(TT, BB, Q)                                                        \
  if ((TT) < 64) gload16(Wc + bQ[Q] + (long)(TT) * 128,                      \
                         (char*)&lds[BB][1][0] + qXo[Q]);

  f32x4 zero = {0.f, 0.f, 0.f, 0.f};
  f32x4 acc[8][4];
  #pragma unroll
  for (int i = 0; i < 8; ++i)
    #pragma unroll
    for (int jj = 0; jj < 4; ++jj) acc[i][jj] = zero;

  const int aro = (wm * 128 + l15) * 128;
  const int bro = (wn * 64 + l15) * 128;
  const int cs0 = (lg << 4) ^ swz;
  const int cs1 = (64 | (lg << 4)) ^ swz;

  SB(0, 0, 0) SB(0, 0, 1) SB(0, 0, 2) SB(0, 0, 3)
  SA(0, 0, 0) SA(0, 0, 1) SA(0, 0, 2) SA(0, 0, 3)
  asm volatile("s_waitcnt vmcnt(0)" ::: "memory");
  __builtin_amdgcn_s_barrier();

  #pragma clang loop unroll(disable)
  for (int t = 0; t < 64; ++t) {
    const int bt = t & 1, nb = bt ^ 1;
    const char* LA = (const char*)&lds[bt][0][0];
    const char* LB = (const char*)&lds[bt][1][0];
    bf16x8 af[4][2], bf0[2][2], bf1[2][2];

    // ---- phase 0 ----
    #pragma unroll
    for (int i = 0; i < 4; ++i) {
      af[i][0] = *(const bf16x8*)(LA + aro + i * 2048 + cs0);
      af[i][1] = *(const bf16x8*)(LA + aro + i * 2048 + cs1);
    }
    #pragma unroll
    for (int jj = 0; jj < 2; ++jj) {
      bf0[jj][0] = *(const bf16x8*)(LB + bro + jj * 2048 + cs0);
      bf0[jj][1] = *(const bf16x8*)(LB + bro + jj * 2048 + cs1);
    }
    SB(t + 1, nb, 0) SB(t + 1, nb, 1) SA(t + 1, nb, 0) SA(t + 1, nb, 2)
    __builtin_amdgcn_s_barrier();
    asm volatile("s_waitcnt lgkmcnt(0)" ::: "memory");
    __builtin_amdgcn_sched_barrier(0);
    __builtin_amdgcn_s_setprio(1);
    #pragma unroll
    for (int i = 0; i < 4; ++i)
      #pragma unroll
      for (int jj = 0; jj < 2; ++jj) {
        acc[i][jj] = __builtin_amdgcn_mfma_f32_16x16x32_bf16(af[i][0], bf0[jj][0], acc[i][jj], 0, 0, 0);
        acc[i][jj] = __builtin_amdgcn_mfma_f32_16x16x32_bf16(af[i][1], bf0[jj][1], acc[i][jj], 0, 0, 0);
      }
    __builtin_amdgcn_s_setprio(0);
    __builtin_amdgcn_s_barrier();

    // ---- phase 1 ----
    #pragma unroll
    for (int jj = 0; jj < 2; ++jj) {
      bf1[jj][0] = *(const bf16x8*)(LB + bro + (2 + jj) * 2048 + cs0);
      bf1[jj][1] = *(const bf16x8*)(LB + bro + (2 + jj) * 2048 + cs1);
    }
    SB(t + 1, nb, 2) SB(t + 1, nb, 3) SA(t + 1, nb, 1) SA(t + 1, nb, 3)
    __builtin_amdgcn_s_barrier();
    asm volatile("s_waitcnt lgkmcnt(0)" ::: "memory");
    __builtin_amdgcn_sched_barrier(0);
    __builtin_amdgcn_s_setprio(1);
    #pragma unroll
    for (int i = 0; i < 4; ++i)
      #pragma unroll
      for (int jj = 0; jj < 2; ++jj) {
        acc[i][2 + jj] = __builtin_amdgcn_mfma_f32_16x16x32_bf16(af[i][0], bf1[jj][0], acc[i][2 + jj], 0, 0, 0);
        acc[i][2 + jj] = __builtin_amdgcn_mfma_f32_16x16x32_bf16(af[i][1], bf1[jj][1], acc[i][2 + jj], 0, 0, 0);
      }
    __builtin_amdgcn_s_setprio(0);
    if (t == 63) {
      asm volatile("s_waitcnt vmcnt(0)" ::: "memory");
    } else {
      asm volatile("s_waitcnt vmcnt(8)" ::: "memory");
    }
    __builtin_amdgcn_sched_barrier(0);
    __builtin_amdgcn_s_barrier();

    // ---- phase 2 ----
    #pragma unroll
    for (int i = 0; i < 4; ++i) {
      af[i][0] = *(const bf16x8*)(LA + aro + (4 + i) * 2048 + cs0);
      af[i][1] = *(const bf16x8*)(LA + aro + (4 + i) * 2048 + cs1);
    }
    __builtin_amdgcn_s_barrier();
    asm volatile("s_waitcnt lgkmcnt(0)" ::: "memory");
    __builtin_amdgcn_sched_barrier(0);
    __builtin_amdgcn_s_setprio(1);
    #pragma unroll
    for (int i = 0; i < 4; ++i)
      #pragma unroll
      for (int jj = 0; jj < 2; ++jj) {
        acc[4 + i][jj] = __builtin_amdgcn_mfma_f32_16x16x32_bf16(af[i][0], bf0[jj][0], acc[4 + i][jj], 0, 0, 0);
        acc[4 + i][jj] = __builtin_amdgcn_mfma_f32_16x16x32_bf16(af[i][1], bf0[jj][1], acc[4 + i][jj], 0, 0, 0);
      }
    __builtin_amdgcn_s_setprio(0);
    __builtin_amdgcn_s_barrier();

    // ---- phase 3 ----
    __builtin_amdgcn_s_setprio(1);
    #pragma unroll
    for (int i = 0; i < 4; ++i)
      #pragma unroll
      for (int jj = 0; jj < 2; ++jj) {
        acc[4 + i][2 + jj] = __builtin_amdgcn_mfma_f32_16x16x32_bf16(af[i][0], bf1[jj][0], acc[4 + i][2 + jj], 0, 0, 0);
        acc[4 + i][2 + jj] = __builtin_amdgcn_mfma_f32_16x16x32_bf16(af[i][1], bf1[jj][1], acc[4 + i][2 + jj], 0, 0, 0);
      }
    __builtin_amdgcn_s_setprio(0);
    if (t < 63) {
      asm volatile("s_waitcnt vmcnt(2)" ::: "memory");
      __builtin_amdgcn_sched_barrier(0);
      __builtin_amdgcn_s_barrier();
    }
  }
#undef SA
#undef SB

  // epilogue: all columns are q -> RoPE (pair = adjacent l15 lane) + write qb
  #pragma unroll
  for (int mr = 0; mr < 8; ++mr) {
    int mbase = tm * 256 + wm * 128 + mr * 16 + lg * 4;
    #pragma unroll
    for (int nr = 0; nr < 4; ++nr) {
      int col = tn * 256 + wn * 64 + nr * 16 + l15;
      float pv[4];
      #pragma unroll
      for (int r = 0; r < 4; ++r) pv[r] = __shfl_xor(acc[mr][nr][r], 1);
      #pragma unroll
      for (int r = 0; r < 4; ++r) {
        int m = mbase + r;
        float v = acc[mr][nr][r];
        int b = m >> 11, s = m & 2047;
        int h = col >> 7, d = col & 127;
        float x1 = (l15 & 1) ? pv[r] : v;
        float x2 = (l15 & 1) ? v : pv[r];
        float inv = __expf(-0.14391157f * (float)(d >> 1));  // 1e4^(-2j/128)
        float sn, cs;
        __sincosf((float)s * inv, &sn, &cs);
        float rr = (l15 & 1) ? (x1 * sn + x2 * cs) : (x1 * cs - x2 * sn);
        qb[((long)((b * 32 + h) * 2048 + s)) * 128 + d] = f2bf(rr);
      }
    }
  }
}

// ---------------- GEMM-KV: 256x128, BK=64, 3-buffer (proven), N=2048 --------
__global__ __launch_bounds__(512, 2) void gemm_kv(
    const short* __restrict__ A, const short* __restrict__ W,
    short* __restrict__ kb, short* __restrict__ vb,
    float* __restrict__ nk, float* __restrict__ nv)
{
  __shared__ short lds[3][24576];  // 3 x 48KB: A at +0 (32KB), B at +32768

  const int tid = threadIdx.x;
  const int lane = tid & 63;
  const int w = tid >> 6;
  const int wm = w >> 1, wn = w & 1;          // 4 x 2 waves
  const int l15 = lane & 15, lg = lane >> 4;
  const int swz = (l15 & 7) << 4;

  int c = blockIdx.x & 7, j = blockIdx.x >> 3;
  const int tm = (c >> 2) * 8 + (j & 7);
  const int tn = (c & 3) * 4 + (j >> 3);     // 16 tn tiles of 128

  const char* Ac = (const char*)A;
  const char* Wc = (const char*)W;

  int aXo[4], bXo[2];
  long aSrc[4], bSrc[2];
  #pragma unroll
  for (int l4 = 0; l4 < 4; ++l4) {
    int X = tid * 16 + l4 * 8192;
    int row = X >> 7;
    int colS = (X & 127) ^ (((X >> 7) & 7) << 4);
    aXo[l4] = X;
    aSrc[l4] = (long)(tm * 256 + row) * 8192 + colS;
  }
  #pragma unroll
  for (int l4 = 0; l4 < 2; ++l4) {
    int X = tid * 16 + l4 * 8192;
    int row = X >> 7;
    int colS = (X & 127) ^ (((X >> 7) & 7) << 4);
    bXo[l4] = X;
    bSrc[l4] = (long)(tn * 128 + row) * 8192 + colS;
  }

#define STAGE(TT, BI)                                                        \
  {                                                                          \
    const long kof_ = (long)(TT) * 128;                                      \
    _Pragma("unroll")                                                        \
    for (int l4 = 0; l4 < 4; ++l4)                                           \
      gload16(Ac + aSrc[l4] + kof_, (char*)&lds[BI][0] + aXo[l4]);           \
    _Pragma("unroll")                                                        \
    for (int l4 = 0; l4 < 2; ++l4)                                           \
      gload16(Wc + bSrc[l4] + kof_, (char*)&lds[BI][0] + 32768 + bXo[l4]);   \
  }

  f32x4 zero = {0.f, 0.f, 0.f, 0.f};
  f32x4 acc[4][4];
  #pragma unroll
  for (int i = 0; i < 4; ++i)
    #pragma unroll
    for (int jj = 0; jj < 4; ++jj) acc[i][jj] = zero;

  const int aro = (wm * 64 + l15) * 128;
  const int bro = 32768 + (wn * 64 + l15) * 128;
  const int cs0 = (lg << 4) ^ swz;
  const int cs1 = (64 | (lg << 4)) ^ swz;

#define MF(a0, a1, MR)                                                       \
  __builtin_amdgcn_s_setprio(1);                                             \
  _Pragma("unroll")                                                          \
  for (int nr = 0; nr < 4; ++nr) {                                           \
    acc[MR][nr] = __builtin_amdgcn_mfma_f32_16x16x32_bf16(                   \
        a0, bfr[nr][0], acc[MR][nr], 0, 0, 0);                               \
    acc[MR][nr] = __builtin_amdgcn_mfma_f32_16x16x32_bf16(                   \
        a1, bfr[nr][1], acc[MR][nr], 0, 0, 0);                               \
  }                                                                          \
  __builtin_amdgcn_s_setprio(0);

#define TILE(T, BI)                                                          \
  {                                                                          \
    const char* L = (const char*)&lds[BI][0];                                \
    bf16x8 bfr[4][2];                                                        \
    _Pragma("unroll")                                                        \
    for (int nr = 0; nr < 4; ++nr) {                                         \
      bfr[nr][0] = *(const bf16x8*)(L + bro + nr * 2048 + cs0);              \
      bfr[nr][1] = *(const bf16x8*)(L + bro + nr * 2048 + cs1);              \
    }                                                                        \
    bf16x8 g0, g1, h0, h1;                                                   \
    g0 = *(const bf16x8*)(L + aro + 0 * 2048 + cs0);                         \
    g1 = *(const bf16x8*)(L + aro + 0 * 2048 + cs1);                         \
    h0 = *(const bf16x8*)(L + aro + 1 * 2048 + cs0);                         \
    h1 = *(const bf16x8*)(L + aro + 1 * 2048 + cs1);                         \
    asm volatile("s_waitcnt lgkmcnt(2)" ::: "memory");                       \
    __builtin_amdgcn_sched_barrier(0);                                       \
    MF(g0, g1, 0)                                                            \
    g0 = *(const bf16x8*)(L + aro + 2 * 2048 + cs0);                         \
    g1 = *(const bf16x8*)(L + aro + 2 * 2048 + cs1);                         \
    asm volatile("s_waitcnt lgkmcnt(2)" ::: "memory");                       \
    __builtin_amdgcn_sched_barrier(0);                                       \
    MF(h0, h1, 1)                                                            \
    h0 = *(const bf16x8*)(L + aro + 3 * 2048 + cs0);                         \
    h1 = *(const bf16x8*)(L + aro + 3 * 2048 + cs1);                         \
    asm volatile("s_waitcnt lgkmcnt(2)" ::: "memory");                       \
    __builtin_amdgcn_sched_barrier(0);                                       \
    MF(g0, g1, 2)                                                            \
    asm volatile("s_waitcnt lgkmcnt(0)" ::: "memory");                       \
    __builtin_amdgcn_sched_barrier(0);                                       \
    MF(h0, h1, 3)                                                            \
    if ((T) < 62) {                                                          \
      asm volatile("s_waitcnt vmcnt(6)" ::: "memory");                       \
    } else if ((T) == 62) {                                                  \
      asm volatile("s_waitcnt vmcnt(0)" ::: "memory");                       \
    }                                                                        \
    if ((T) < 63) __builtin_amdgcn_s_barrier();                              \
    if ((T) < 61) { STAGE((T) + 3, BI) }                                     \
  }

  STAGE(0, 0)
  STAGE(1, 1)
  STAGE(2, 2)
  asm volatile("s_waitcnt vmcnt(12)" ::: "memory");
  __builtin_amdgcn_s_barrier();

  #pragma clang loop unroll(disable)
  for (int t3 = 0; t3 < 63; t3 += 3) {
    TILE(t3 + 0, 0)
    TILE(t3 + 1, 1)
    TILE(t3 + 2, 2)
  }
  TILE(63, 0)

#undef STAGE
#undef TILE
#undef MF

  // epilogue: col 0..1023 = k (RoPE + nk), 1024..2047 = v (nv + vb^T)
  #pragma unroll
  for (int mr = 0; mr < 4; ++mr) {
    int mbase = tm * 256 + wm * 64 + mr * 16 + lg * 4;
    #pragma unroll
    for (int nr = 0; nr < 4; ++nr) {
      int col = tn * 128 + wn * 64 + nr * 16 + l15;
      float pv[4];
      #pragma unroll
      for (int r = 0; r < 4; ++r) pv[r] = __shfl_xor(acc[mr][nr][r], 1);
      #pragma unroll
      for (int r = 0; r < 4; ++r) {
        int m = mbase + r;
        float v = acc[mr][nr][r];
        int b = m >> 11, s = m & 2047;
        if (col < 1024) {  // k: RoPE
          int h = col >> 7, d = col & 127;
          float x1 = (l15 & 1) ? pv[r] : v;
          float x2 = (l15 & 1) ? v : pv[r];
          float inv = __expf(-0.14391157f * (float)(d >> 1));
          float sn, cs;
          __sincosf((float)s * inv, &sn, &cs);
          float rr = (l15 & 1) ? (x1 * sn + x2 * cs) : (x1 * cs - x2 * sn);
          long o = ((long)((b * 8 + h) * 2048 + s)) * 128 + d;
          kb[o] = f2bf(rr);
          nk[o] = v;  // PRE-rope
        } else {
          int c2 = col - 1024;
          int h = c2 >> 7, d = c2 & 127;
          long o = ((long)((b * 8 + h) * 2048 + s)) * 128 + d;
          nv[o] = v;
          vb[((long)((b * 8 + h) * 128 + d)) * 2048 + s] = f2bf(v);  // [b][hkv][d][s]
        }
      }
    }
  }
}

// ---------------- GEMM2: out-proj. 256x256, 8-phase (proven) ----------------
__global__ __launch_bounds__(512, 2) void gemm_out(
    const short* __restrict__ A, const short* __restrict__ W,
    float* __restrict__ Cout)
{
  __shared__ __align__(16) short lds[2][2][16384];  // [buf][0=A,1=B]

  const int tid = threadIdx.x;
  const int lane = tid & 63;
  const int w = tid >> 6;
  const int wm = w >> 2, wn = w & 3;
  const int l15 = lane & 15, lg = lane >> 4;
  const int swz = (l15 & 7) << 4;

  int c = blockIdx.x & 7, j = blockIdx.x >> 3;
  const int tm = (c >> 2) * 8 + (j & 7);
  const int tn = (c & 3) * 4 + (j >> 3);

  const char* Ac = (const char*)A;
  const char* Wc = (const char*)W;

  int qXo[4];
  long aQ[4], bQ[4];
  #pragma unroll
  for (int q = 0; q < 4; ++q) {
    int X = q * 8192 + tid * 16;
    int row = X >> 7;
    int colS = (X & 127) ^ ((row & 7) << 4);
    qXo[q] = X;
    aQ[q] = (long)(tm * 256 + row) * 8192 + colS;
    bQ[q] = (long)(tn * 256 + row) * 8192 + colS;
  }

#define SA(TT, BB, Q)                                                        \
  if ((TT) < 64) gload16(Ac + aQ[Q] + (long)(TT) * 128,                      \
                         (char*)&lds[BB][0][0] + qXo[Q]);
#define SB(TT, BB, Q)                                                        \
  if ((TT) < 64) gload16(Wc + bQ[Q] + (long)(TT) * 128,                      \
                         (char*)&lds[BB][1][0] + qXo[Q]);

  f32x4 zero = {0.f, 0.f, 0.f, 0.f};
  f32x4 acc[8][4];
  #pragma unroll
  for (int i = 0; i < 8; ++i)
    #pragma unroll
    for (int jj = 0; jj < 4; ++jj) acc[i][jj] = zero;

  const int aro = (wm * 128 + l15) * 128;
  const int bro = (wn * 64 + l15) * 128;
  const int cs0 = (lg << 4) ^ swz;
  const int cs1 = (64 | (lg << 4)) ^ swz;

  SB(0, 0, 0) SB(0, 0, 1) SB(0, 0, 2) SB(0, 0, 3)
  SA(0, 0, 0) SA(0, 0, 1) SA(0, 0, 2) SA(0, 0, 3)
  asm volatile("s_waitcnt vmcnt(0)" ::: "memory");
  __builtin_amdgcn_s_barrier();

  #pragma clang loop unroll(disable)
  for (int t = 0; t < 64; ++t) {
    const int bt = t & 1, nb = bt ^ 1;
    const char* LA = (const char*)&lds[bt][0][0];
    const char* LB = (const char*)&lds[bt][1][0];
    bf16x8 af[4][2], bf0[2][2], bf1[2][2];

    #pragma unroll
    for (int i = 0; i < 4; ++i) {
      af[i][0] = *(const bf16x8*)(LA + aro + i * 2048 + cs0);
      af[i][1] = *(const bf16x8*)(LA + aro + i * 2048 + cs1);
    }
    #pragma unroll
    for (int jj = 0; jj < 2; ++jj) {
      bf0[jj][0] = *(const bf16x8*)(LB + bro + jj * 2048 + cs0);
      bf0[jj][1] = *(const bf16x8*)(LB + bro + jj * 2048 + cs1);
    }
    SB(t + 1, nb, 0) SB(t + 1, nb, 1) SA(t + 1, nb, 0) SA(t + 1, nb, 2)
    __builtin_amdgcn_s_barrier();
    asm volatile("s_waitcnt lgkmcnt(0)" ::: "memory");
    __builtin_amdgcn_sched_barrier(0);
    __builtin_amdgcn_s_setprio(1);
    #pragma unroll
    for (int i = 0; i < 4; ++i)
      #pragma unroll
      for (int jj = 0; jj < 2; ++jj) {
        acc[i][jj] = __builtin_amdgcn_mfma_f32_16x16x32_bf16(af[i][0], bf0[jj][0], acc[i][jj], 0, 0, 0);
        acc[i][jj] = __builtin_amdgcn_mfma_f32_16x16x32_bf16(af[i][1], bf0[jj][1], acc[i][jj], 0, 0, 0);
      }
    __builtin_amdgcn_s_setprio(0);
    __builtin_amdgcn_s_barrier();

    #pragma unroll
    for (int jj = 0; jj < 2; ++jj) {
      bf1[jj][0] = *(const bf16x8*)(LB + bro + (2 + jj) * 2048 + cs0);
      bf1[jj][1] = *(const bf16x8*)(LB + bro + (2 + jj) * 2048 + cs1);
    }
    SB(t + 1, nb, 2) SB(t + 1, nb, 3) SA(t + 1, nb, 1) SA(t + 1, nb, 3)
    __builtin_amdgcn_s_barrier();
    asm volatile("s_waitcnt lgkmcnt(0)" ::: "memory");
    __builtin_amdgcn_sched_barrier(0);
    __builtin_amdgcn_s_setprio(1);
    #pragma unroll
    for (int i = 0; i < 4; ++i)
      #pragma unroll
      for (int jj = 0; jj < 2; ++jj) {
        acc[i][2 + jj] = __builtin_amdgcn_mfma_f32_16x16x32_bf16(af[i][0], bf1[jj][0], acc[i][2 + jj], 0, 0, 0);
        acc[i][2 + jj] = __builtin_amdgcn_mfma_f32_16x16x32_bf16(af[i][1], bf1[jj][1], acc[i][2 + jj], 0, 0, 0);
      }
    __builtin_amdgcn_s_setprio(0);
    if (t == 63) {
      asm volatile("s_waitcnt vmcnt(0)" ::: "memory");
    } else {
      asm volatile("s_waitcnt vmcnt(8)" ::: "memory");
    }
    __builtin_amdgcn_sched_barrier(0);
    __builtin_amdgcn_s_barrier();

    #pragma unroll
    for (int i = 0; i < 4; ++i) {
      af[i][0] = *(const bf16x8*)(LA + aro + (4 + i) * 2048 + cs0);
      af[i][1] = *(const bf16x8*)(LA + aro + (4 + i) * 2048 + cs1);
    }
    __builtin_amdgcn_s_barrier();
    asm volatile("s_waitcnt lgkmcnt(0)" ::: "memory");
    __builtin_amdgcn_sched_barrier(0);
    __builtin_amdgcn_s_setprio(1);
    #pragma unroll
    for (int i = 0; i < 4; ++i)
      #pragma unroll
      for (int jj = 0; jj < 2; ++jj) {
        acc[4 + i][jj] = __builtin_amdgcn_mfma_f32_16x16x32_bf16(af[i][0], bf0[jj][0], acc[4 + i][jj], 0, 0, 0);
        acc[4 + i][jj] = __builtin_amdgcn_mfma_f32_16x16x32_bf16(af[i][1], bf0[jj][1], acc[4 + i][jj], 0, 0, 0);
      }
    __builtin_amdgcn_s_setprio(0);
    __builtin_amdgcn_s_barrier();

    __builtin_amdgcn_s_setprio(1);
    #pragma unroll
    for (int i = 0; i < 4; ++i)
      #pragma unroll
      for (int jj = 0; jj < 2; ++jj) {
        acc[4 + i][2 + jj] = __builtin_amdgcn_mfma_f32_16x16x32_bf16(af[i][0], bf1[jj][0], acc[4 + i][2 + jj], 0, 0, 0);
        acc[4 + i][2 + jj] = __builtin_amdgcn_mfma_f32_16x16x32_bf16(af[i][1], bf1[jj][1], acc[4 + i][2 + jj], 0, 0, 0);
      }
    __builtin_amdgcn_s_setprio(0);
    if (t < 63) {
      asm volatile("s_waitcnt vmcnt(2)" ::: "memory");
      __builtin_amdgcn_sched_barrier(0);
      __builtin_amdgcn_s_barrier();
    }
  }
#undef SA
#undef SB

  #pragma unroll
  for (int mr = 0; mr < 8; ++mr) {
    int mbase = tm * 256 + wm * 128 + mr * 16 + lg * 4;
    #pragma unroll
    for (int nr = 0; nr < 4; ++nr) {
      int col = tn * 256 + wn * 64 + nr * 16 + l15;
      #pragma unroll
      for (int r = 0; r < 4; ++r)
        Cout[(long)(mbase + r) * 4096 + col] = acc[mr][nr][r];
    }
  }
}

// ---------------- Flash attention v8: 8 waves / 512 thr, Q-tile 256 ---------
// grid 512; qt = 7-(bid>>6) (LPT), hb = bid&63. Wave w owns q rows
// qt*256 + w*32 .. +31. KV = 64, K/V double-buffered gload_lds staging now
// amortized over 8 waves (2 chunks/thread). Inner loop identical to v7.
__global__ __launch_bounds__(512) void flash_kernel(
    const short* __restrict__ qb, const short* __restrict__ kb,
    const short* __restrict__ vt, short* __restrict__ ao)
{
  const int bid = blockIdx.x;
  const int qt = 7 - (bid >> 6);    // LPT: heaviest blocks dispatch first
  const int hb = bid & 63;
  const int h = hb & 31, b = hb >> 5;
  const int hkv = h >> 2;
  const int tid = threadIdx.x, w = tid >> 6, lane = tid & 63;
  const int l31 = lane & 31, hi = lane >> 5;
  const int hi16 = hi * 16;
  const int q0 = qt * 256 + w * 32;
  const int q_abs = q0 + l31;

  const short* Q  = qb + (long)(b * 32 + h) * 2048 * 128;
  const char*  Kg = (const char*)(kb + (long)(b * 8 + hkv) * 2048 * 128);
  const char*  Vg = (const char*)(vt + (long)(b * 8 + hkv) * 2048 * 128);  // [d][s]

  __shared__ short Ks[2][64 * 128];  // [kv][d], 16B chunks XOR-swizzled (kv&15)
  __shared__ short Vs[2][128 * 64];  // [d][kv], 16B chunks XOR-swizzled (d&7)

  // staging: 512 threads x 2 chunks x 16B = 16KB per buffer
  int skX[2], svRow[2], svCol[2], Xo[2];
  #pragma unroll
  for (int i2 = 0; i2 < 2; ++i2) {
    int X = tid * 16 + i2 * 8192;
    Xo[i2] = X;
    skX[i2] = X ^ (((X >> 8) & 15) << 4);
    int sv = X ^ (((X >> 7) & 7) << 4);
    svRow[i2] = sv >> 7;
    svCol[i2] = sv & 127;
  }

  bf16x8 qf[8];
  #pragma unroll
  for (int c = 0; c < 8; ++c)
    qf[c] = *(const bf16x8*)&Q[(long)q_abs * 128 + c * 16 + hi * 8];

  f32x16 o[4];
  #pragma unroll
  for (int db = 0; db < 4; ++db)
    #pragma unroll
    for (int r = 0; r < 16; ++r) o[db][r] = 0.f;
  float m_ = -3e38f, l_ = 0.f;

  const float scale2 = 0.08838834764831845f * 1.4426950408889634f;
  const int nt = 4 * (qt + 1);
  const int kswk = (l31 & 15) << 4;
  const int kswv = (l31 & 7) << 4;

  #pragma unroll
  for (int i2 = 0; i2 < 2; ++i2) {
    gload16(Kg + skX[i2], (char*)Ks[0] + Xo[i2]);
    gload16(Vg + ((long)svRow[i2] * 4096 + svCol[i2]), (char*)Vs[0] + Xo[i2]);
  }

  for (int t = 0; t < nt; ++t) {
    const int kv0 = t * 64;
    const int cur = t & 1;
    __syncthreads();
    if (t + 1 < nt) {
      const long kvb = (long)(kv0 + 64);
      #pragma unroll
      for (int i2 = 0; i2 < 2; ++i2) {
        gload16(Kg + kvb * 256 + skX[i2], (char*)Ks[cur ^ 1] + Xo[i2]);
        gload16(Vg + ((long)svRow[i2] * 4096 + kvb * 2 + svCol[i2]),
                (char*)Vs[cur ^ 1] + Xo[i2]);
      }
    }
    if (kv0 > q0 + 31) continue;

    f32x16 s0, s1;
    #pragma unroll
    for (int r = 0; r < 16; ++r) { s0[r] = 0.f; s1[r] = 0.f; }
    const char* kbase = (const char*)Ks[cur] + l31 * 256;
    __builtin_amdgcn_s_setprio(1);
    #pragma unroll
    for (int c = 0; c < 8; ++c) {
      bf16x8 kf0 = *(const bf16x8*)(kbase + ((c * 32 + hi16) ^ kswk));
      bf16x8 kf1 = *(const bf16x8*)(kbase + 8192 + ((c * 32 + hi16) ^ kswk));
      s0 = __builtin_amdgcn_mfma_f32_32x32x16_bf16(kf0, qf[c], s0, 0, 0, 0);
      s1 = __builtin_amdgcn_mfma_f32_32x32x16_bf16(kf1, qf[c], s1, 0, 0, 0);
    }
    __builtin_amdgcn_s_setprio(0);

    const bool diag = (kv0 + 63 > q0);
    if (diag) {
      #pragma unroll
      for (int r = 0; r < 16; ++r) {
        int krow = (r & 3) + 8 * (r >> 2) + 4 * hi;
        if (kv0 + krow > q_abs)      s0[r] = -3e38f;
        if (kv0 + 32 + krow > q_abs) s1[r] = -3e38f;
      }
    }
    // tree max
    float tm_[8];
    #pragma unroll
    for (int r = 0; r < 8; ++r)
      tm_[r] = fmaxf(fmaxf(s0[r], s0[r + 8]), fmaxf(s1[r], s1[r + 8]));
    #pragma unroll
    for (int st = 4; st >= 1; st >>= 1)
      #pragma unroll
      for (int r = 0; r < st; ++r) tm_[r] = fmaxf(tm_[r], tm_[r + st]);
    float mx = tm_[0] * scale2;
    mx = fmaxf(mx, __shfl_xor(mx, 32));
    int need = mx > m_ + 11.5f;
    if (__any(need)) {
      float mn = fmaxf(m_, mx);
      float fac = exp2f(m_ - mn);
      m_ = mn;
      l_ *= fac;
      #pragma unroll
      for (int db = 0; db < 4; ++db)
        #pragma unroll
        for (int r = 0; r < 16; ++r) o[db][r] *= fac;
    }
    // exp2 + tree sum
    float ts[8];
    #pragma unroll
    for (int r = 0; r < 16; ++r) {
      s0[r] = exp2f(fmaf(s0[r], scale2, -m_));
      s1[r] = exp2f(fmaf(s1[r], scale2, -m_));
    }
    #pragma unroll
    for (int r = 0; r < 8; ++r)
      ts[r] = (s0[r] + s0[r + 8]) + (s1[r] + s1[r + 8]);
    #pragma unroll
    for (int st = 4; st >= 1; st >>= 1)
      #pragma unroll
      for (int r = 0; r < st; ++r) ts[r] += ts[r + st];
    float rs = ts[0];
    rs += __shfl_xor(rs, 32);
    l_ += rs;

    const char* vbase = (const char*)Vs[cur] + l31 * 128;
    #pragma unroll
    for (int t2 = 0; t2 < 2; ++t2) {
      const f32x16 sp = t2 ? s1 : s0;
      unsigned wd[8];
      #pragma unroll
      for (int jj = 0; jj < 8; ++jj) wd[jj] = cvtpk(sp[2 * jj], sp[2 * jj + 1]);
      unsigned u0 = hi ? wd[0] : wd[2];
      unsigned u1 = hi ? wd[1] : wd[3];
      unsigned u2 = hi ? wd[4] : wd[6];
      unsigned u3 = hi ? wd[5] : wd[7];
      unsigned x0 = (unsigned)__shfl_xor((int)u0, 32);
      unsigned x1 = (unsigned)__shfl_xor((int)u1, 32);
      unsigned x2 = (unsigned)__shfl_xor((int)u2, 32);
      unsigned x3 = (unsigned)__shfl_xor((int)u3, 32);
      BW f0, f1;
      f0.u[0] = hi ? x0 : wd[0];
      f0.u[1] = hi ? x1 : wd[1];
      f0.u[2] = hi ? wd[2] : x0;
      f0.u[3] = hi ? wd[3] : x1;
      f1.u[0] = hi ? x2 : wd[4];
      f1.u[1] = hi ? x3 : wd[5];
      f1.u[2] = hi ? wd[6] : x2;
      f1.u[3] = hi ? wd[7] : x3;
      __builtin_amdgcn_s_setprio(1);
      #pragma unroll
      for (int cc = 0; cc < 2; ++cc) {
        const BW& fr = cc ? f1 : f0;
        #pragma unroll
        for (int db = 0; db < 4; ++db) {
          bf16x8 vf = *(const bf16x8*)(vbase + db * 4096 +
                                       ((t2 * 64 + cc * 32 + hi16) ^ kswv));
          o[db] = __builtin_amdgcn_mfma_f32_32x32x16_bf16(vf, fr.v, o[db], 0, 0, 0);
        }
      }
      __builtin_amdgcn_s_setprio(0);
    }
  }

  float invl = 1.0f / l_;
  const long aorow = ((long)(b * 2048 + q_abs)) * 4096 + h * 128 + hi * 4;
  #pragma unroll
  for (int db = 0; db < 4; ++db)
    #pragma unroll
    for (int r = 0; r < 16; ++r) {
      int doff = db * 32 + (r & 3) + 8 * (r >> 2);
      ao[aorow + doff] = f2bf(o[db][r] * invl);
    }
}

// ---------------- launcher --------------------------------------------------
extern "C" void kernel_launch(void* const* d_in, const int* in_sizes, int n_in,
                              void* d_out, int out_size, void* d_ws, size_t ws_size,
                              hipStream_t stream) {
  const float* x  = (const float*)d_in[0];
  const float* wq = (const float*)d_in[1];
  const float* wk = (const float*)d_in[2];
  const float* wv = (const float*)d_in[3];
  const float* wo = (const float*)d_in[4];
  float* out = (float*)d_out;

  char* ws = (char*)d_ws;
  short* xb    = (short*)(ws);               // x bf16; later reused as attn_out
  short* wqkvb = (short*)(ws + 33554432);    // wq|wk|wv bf16 (6144x4096)
  short* wob   = (short*)(ws + 83886080);
  short* qb    = (short*)(ws + 117440512);   // (B,H,S,D) post-RoPE
  short* kb    = (short*)(ws + 150994944);   // (B,Hkv,S,D) post-RoPE
  short* vb    = (short*)(ws + 159383552);   // (B,Hkv,D,S)  TRANSPOSED
  short* ao    = xb;

  float* nk = out + 16777216;  // new_k fp32 (B,Hkv,S,D) PRE-rope
  float* nv = out + 20971520;  // new_v fp32

  cast_all<<<28672, 256, 0, stream>>>(x, wq, wk, wv, wo, xb, wqkvb, wob);

  gemm_q<<<256, 512, 0, stream>>>(xb, wqkvb, qb);
  gemm_kv<<<256, 512, 0, stream>>>(xb, wqkvb + 16777216, kb, vb, nk, nv);
  flash_kernel<<<512, 512, 0, stream>>>(qb, kb, vb, ao);
  gemm_out<<<256, 512, 0, stream>>>(ao, wob, out);
}

// Round 18
// 478.698 us; speedup vs baseline: 1.1567x; 1.0089x over previous
//
#include <hip/hip_runtime.h>
#include <hip/hip_bf16.h>

typedef __attribute__((ext_vector_type(8)))  short   s16x8;
typedef __attribute__((ext_vector_type(8)))  __bf16  bf16x8;
typedef __attribute__((ext_vector_type(4)))  float   f32x4;
typedef __attribute__((ext_vector_type(16))) float   f32x16;

#define DEV static __device__ __forceinline__

DEV short f2bf(float f) {
  unsigned u = __builtin_bit_cast(unsigned, f);
  u = (u + 0x7fff + ((u >> 16) & 1)) >> 16;
  return (short)u;
}
DEV float bf2f(short s) {
  unsigned u = ((unsigned)(unsigned short)s) << 16;
  return __builtin_bit_cast(float, u);
}

DEV void gload16(const void* g, void* l) {
  __builtin_amdgcn_global_load_lds(
      (const __attribute__((address_space(1))) unsigned int*)g,
      (__attribute__((address_space(3))) unsigned int*)l, 16, 0, 0);
}

DEV unsigned cvtpk(float lo, float hi) {
  unsigned r;
  asm("v_cvt_pk_bf16_f32 %0, %1, %2" : "=v"(r) : "v"(lo), "v"(hi));
  return r;
}

typedef union { unsigned u[4]; bf16x8 v; } BW;

// ---------------- fused cast fp32 -> bf16 for all 5 inputs ------------------
__global__ __launch_bounds__(256) void cast_all(
    const float* __restrict__ x,  const float* __restrict__ wq,
    const float* __restrict__ wk, const float* __restrict__ wv,
    const float* __restrict__ wo,
    short* __restrict__ xb, short* __restrict__ wqkvb, short* __restrict__ wob) {
  long i = (long)blockIdx.x * 256 + threadIdx.x;  // vector index
  const float* src;
  short* dst;
  long off;
  if (i < 2097152)       { src = x;  dst = xb;               off = i; }
  else if (i < 4194304)  { src = wq; dst = wqkvb;            off = i - 2097152; }
  else if (i < 4718592)  { src = wk; dst = wqkvb + 16777216; off = i - 4194304; }
  else if (i < 5242880)  { src = wv; dst = wqkvb + 20971520; off = i - 4718592; }
  else                   { src = wo; dst = wob;              off = i - 5242880; }
  long e = off * 8;
  float4 a = *(const float4*)(src + e);
  float4 b = *(const float4*)(src + e + 4);
  s16x8 o;
  o[0] = f2bf(a.x); o[1] = f2bf(a.y); o[2] = f2bf(a.z); o[3] = f2bf(a.w);
  o[4] = f2bf(b.x); o[5] = f2bf(b.y); o[6] = f2bf(b.z); o[7] = f2bf(b.w);
  *(s16x8*)(dst + e) = o;
}

// ======== GEMM 256x256, BK=32, 3-buffer 1-barrier/tile engine ===============
// gemm_kv's PROVEN TILE discipline at BN=256: per K-tile ONE vmcnt(4) + ONE
// barrier + STAGE(t+3); ds_reads software-pipelined on lgkmcnt(1)
// (1-outstanding groups, issue order pinned, DS completes in-order).
// 8 waves 2Mx4N, wave tile 128x64, 32 MFMA / 12 b128 per A-row phase.
// LDS 3 x (A 16K + B 16K) = 96KB. Swizzle for 64B rows: col ^= ((row>>1)&3)<<4
// both-sides. K=4096 -> 128 tiles = 3*42+2.
#define G_PROLOG                                                             \
  __shared__ __align__(16) short lds[3][16384];                              \
  const int tid = threadIdx.x;                                               \
  const int lane = tid & 63;                                                 \
  const int w = tid >> 6;                                                    \
  const int wm = w >> 2, wn = w & 3;                                         \
  const int l15 = lane & 15, lg = lane >> 4;                                 \
  int c = blockIdx.x & 7, j = blockIdx.x >> 3;                               \
  const int tm = (c >> 2) * 8 + (j & 7);                                     \
  const int tn = (c & 3) * 4 + (j >> 3);                                     \
  const char* Ac = (const char*)A;                                           \
  const char* Wc = (const char*)W;                                           \
  int Xl[2];                                                                 \
  long aSrc[2], bSrc[2];                                                     \
  _Pragma("unroll")                                                          \
  for (int q = 0; q < 2; ++q) {                                              \
    int X = tid * 16 + q * 8192;                                             \
    int row = X >> 6;                                                        \
    int colS = (X & 63) ^ (((X >> 7) & 3) << 4);                             \
    Xl[q] = X;                                                               \
    aSrc[q] = (long)(tm * 256 + row) * 8192 + colS;                          \
    bSrc[q] = (long)(tn * 256 + row) * 8192 + colS;                          \
  }                                                                          \
  f32x4 zero = {0.f, 0.f, 0.f, 0.f};                                         \
  f32x4 acc[8][4];                                                           \
  _Pragma("unroll")                                                          \
  for (int i = 0; i < 8; ++i)                                                \
    _Pragma("unroll")                                                        \
    for (int jj = 0; jj < 4; ++jj) acc[i][jj] = zero;                        \
  const int rcol = (lg << 4) ^ (((l15 >> 1) & 3) << 4);                      \
  const int aBase = (wm * 128 + l15) * 64 + rcol;                            \
  const int bBase = 16384 + (wn * 64 + l15) * 64 + rcol;

#define G_STAGE(TT, BI)                                                      \
  {                                                                          \
    const long kof_ = (long)(TT) * 64;                                       \
    _Pragma("unroll")                                                        \
    for (int q = 0; q < 2; ++q)                                              \
      gload16(Ac + aSrc[q] + kof_, (char*)&lds[BI][0] + Xl[q]);              \
    _Pragma("unroll")                                                        \
    for (int q = 0; q < 2; ++q)                                              \
      gload16(Wc + bSrc[q] + kof_, (char*)&lds[BI][0] + 16384 + Xl[q]);      \
  }

#define G_MF4(AX, MR)                                                        \
  __builtin_amdgcn_s_setprio(1);                                             \
  acc[MR][0] = __builtin_amdgcn_mfma_f32_16x16x32_bf16(AX, bfr0, acc[MR][0], 0, 0, 0); \
  acc[MR][1] = __builtin_amdgcn_mfma_f32_16x16x32_bf16(AX, bfr1, acc[MR][1], 0, 0, 0); \
  acc[MR][2] = __builtin_amdgcn_mfma_f32_16x16x32_bf16(AX, bfr2, acc[MR][2], 0, 0, 0); \
  acc[MR][3] = __builtin_amdgcn_mfma_f32_16x16x32_bf16(AX, bfr3, acc[MR][3], 0, 0, 0); \
  __builtin_amdgcn_s_setprio(0);

#define G_PSTEP(K)                                                           \
  a##K = *(const bf16x8*)(LA + aBase + (K) * 1024);                          \
  asm volatile("s_waitcnt lgkmcnt(1)" ::: "memory");                         \
  __builtin_amdgcn_sched_barrier(0);

#define G_TILE(T, BI)                                                        \
  {                                                                          \
    const char* LA = (const char*)&lds[BI][0];                               \
    bf16x8 bfr0 = *(const bf16x8*)(LA + bBase + 0 * 1024);                   \
    bf16x8 bfr1 = *(const bf16x8*)(LA + bBase + 1 * 1024);                   \
    bf16x8 bfr2 = *(const bf16x8*)(LA + bBase + 2 * 1024);                   \
    bf16x8 bfr3 = *(const bf16x8*)(LA + bBase + 3 * 1024);                   \
    bf16x8 a0, a1, a2, a3, a4, a5, a6, a7;                                   \
    a0 = *(const bf16x8*)(LA + aBase + 0 * 1024);                            \
    asm volatile("" ::: "memory");                                           \
    G_PSTEP(1) G_MF4(a0, 0)                                                  \
    G_PSTEP(2) G_MF4(a1, 1)                                                  \
    G_PSTEP(3) G_MF4(a2, 2)                                                  \
    G_PSTEP(4) G_MF4(a3, 3)                                                  \
    G_PSTEP(5) G_MF4(a4, 4)                                                  \
    G_PSTEP(6) G_MF4(a5, 5)                                                  \
    G_PSTEP(7) G_MF4(a6, 6)                                                  \
    asm volatile("s_waitcnt lgkmcnt(0)" ::: "memory");                       \
    __builtin_amdgcn_sched_barrier(0);                                       \
    G_MF4(a7, 7)                                                             \
    if ((T) < 126) {                                                         \
      asm volatile("s_waitcnt vmcnt(4)" ::: "memory");                       \
    } else if ((T) == 126) {                                                 \
      asm volatile("s_waitcnt vmcnt(0)" ::: "memory");                       \
    }                                                                        \
    if ((T) < 127) __builtin_amdgcn_s_barrier();                             \
    if ((T) < 125) { G_STAGE((T) + 3, BI) }                                  \
  }

#define G_LOOP                                                               \
  G_STAGE(0, 0)                                                              \
  G_STAGE(1, 1)                                                              \
  G_STAGE(2, 2)                                                              \
  asm volatile("s_waitcnt vmcnt(8)" ::: "memory");                           \
  __builtin_amdgcn_s_barrier();                                              \
  _Pragma("clang loop unroll(disable)")                                      \
  for (int t3 = 0; t3 < 126; t3 += 3) {                                      \
    G_TILE(t3 + 0, 0)                                                        \
    G_TILE(t3 + 1, 1)                                                        \
    G_TILE(t3 + 2, 2)                                                        \
  }                                                                          \
  G_TILE(126, 0)                                                             \
  G_TILE(127, 1)

// ---------------- GEMM-Q: q projection + RoPE epilogue ----------------------
__global__ __launch_bounds__(512, 2) void gemm_q(
    const short* __restrict__ A, const short* __restrict__ W,
    short* __restrict__ qb)
{
  G_PROLOG
  G_LOOP
  // epilogue: all columns are q -> RoPE (pair = adjacent l15 lane) + write qb
  #pragma unroll
  for (int mr = 0; mr < 8; ++mr) {
    int mbase = tm * 256 + wm * 128 + mr * 16 + lg * 4;
    #pragma unroll
    for (int nr = 0; nr < 4; ++nr) {
      int col = tn * 256 + wn * 64 + nr * 16 + l15;
      float pv[4];
      #pragma unroll
      for (int r = 0; r < 4; ++r) pv[r] = __shfl_xor(acc[mr][nr][r], 1);
      #pragma unroll
      for (int r = 0; r < 4; ++r) {
        int m = mbase + r;
        float v = acc[mr][nr][r];
        int b = m >> 11;
        int s = m & 2047;
        int h = col >> 7, d = col & 127;
        float x1 = (l15 & 1) ? pv[r] : v;
        float x2 = (l15 & 1) ? v : pv[r];
        float inv = __expf(-0.14391157f * (float)(d >> 1));
        float sn, cs;
        __sincosf((float)s * inv, &sn, &cs);
        float rr = (l15 & 1) ? (x1 * sn + x2 * cs) : (x1 * cs - x2 * sn);
        qb[((long)((b * 32 + h) * 2048 + s)) * 128 + d] = f2bf(rr);
      }
    }
  }
}

// ---------------- GEMM-OUT: out projection, plain fp32 epilogue -------------
__global__ __launch_bounds__(512, 2) void gemm_out(
    const short* __restrict__ A, const short* __restrict__ W,
    float* __restrict__ Cout)
{
  G_PROLOG
  G_LOOP
  #pragma unroll
  for (int mr = 0; mr < 8; ++mr) {
    int mbase = tm * 256 + wm * 128 + mr * 16 + lg * 4;
    #pragma unroll
    for (int nr = 0; nr < 4; ++nr) {
      int col = tn * 256 + wn * 64 + nr * 16 + l15;
      #pragma unroll
      for (int r = 0; r < 4; ++r)
        Cout[(long)(mbase + r) * 4096 + col] = acc[mr][nr][r];
    }
  }
}

#undef G_PROLOG
#undef G_STAGE
#undef G_TILE
#undef G_MF4
#undef G_PSTEP
#undef G_LOOP

// ---------------- GEMM-KV: 256x128, BK=64, 3-buffer (proven), N=2048 --------
__global__ __launch_bounds__(512, 2) void gemm_kv(
    const short* __restrict__ A, const short* __restrict__ W,
    short* __restrict__ kb, short* __restrict__ vb,
    float* __restrict__ nk, float* __restrict__ nv)
{
  __shared__ short lds[3][24576];  // 3 x 48KB: A at +0 (32KB), B at +32768

  const int tid = threadIdx.x;
  const int lane = tid & 63;
  const int w = tid >> 6;
  const int wm = w >> 1, wn = w & 1;          // 4 x 2 waves
  const int l15 = lane & 15, lg = lane >> 4;
  const int swz = (l15 & 7) << 4;

  int c = blockIdx.x & 7, j = blockIdx.x >> 3;
  const int tm = (c >> 2) * 8 + (j & 7);
  const int tn = (c & 3) * 4 + (j >> 3);     // 16 tn tiles of 128

  const char* Ac = (const char*)A;
  const char* Wc = (const char*)W;

  int aXo[4], bXo[2];
  long aSrc[4], bSrc[2];
  #pragma unroll
  for (int l4 = 0; l4 < 4; ++l4) {
    int X = tid * 16 + l4 * 8192;
    int row = X >> 7;
    int colS = (X & 127) ^ (((X >> 7) & 7) << 4);
    aXo[l4] = X;
    aSrc[l4] = (long)(tm * 256 + row) * 8192 + colS;
  }
  #pragma unroll
  for (int l4 = 0; l4 < 2; ++l4) {
    int X = tid * 16 + l4 * 8192;
    int row = X >> 7;
    int colS = (X & 127) ^ (((X >> 7) & 7) << 4);
    bXo[l4] = X;
    bSrc[l4] = (long)(tn * 128 + row) * 8192 + colS;
  }

#define STAGE(TT, BI)                                                        \
  {                                                                          \
    const long kof_ = (long)(TT) * 128;                                      \
    _Pragma("unroll")                                                        \
    for (int l4 = 0; l4 < 4; ++l4)                                           \
      gload16(Ac + aSrc[l4] + kof_, (char*)&lds[BI][0] + aXo[l4]);           \
    _Pragma("unroll")                                                        \
    for (int l4 = 0; l4 < 2; ++l4)                                           \
      gload16(Wc + bSrc[l4] + kof_, (char*)&lds[BI][0] + 32768 + bXo[l4]);   \
  }

  f32x4 zero = {0.f, 0.f, 0.f, 0.f};
  f32x4 acc[4][4];
  #pragma unroll
  for (int i = 0; i < 4; ++i)
    #pragma unroll
    for (int jj = 0; jj < 4; ++jj) acc[i][jj] = zero;

  const int aro = (wm * 64 + l15) * 128;
  const int bro = 32768 + (wn * 64 + l15) * 128;
  const int cs0 = (lg << 4) ^ swz;
  const int cs1 = (64 | (lg << 4)) ^ swz;

#define MF(a0, a1, MR)                                                       \
  __builtin_amdgcn_s_setprio(1);                                             \
  _Pragma("unroll")                                                          \
  for (int nr = 0; nr < 4; ++nr) {                                           \
    acc[MR][nr] = __builtin_amdgcn_mfma_f32_16x16x32_bf16(                   \
        a0, bfr[nr][0], acc[MR][nr], 0, 0, 0);                               \
    acc[MR][nr] = __builtin_amdgcn_mfma_f32_16x16x32_bf16(                   \
        a1, bfr[nr][1], acc[MR][nr], 0, 0, 0);                               \
  }                                                                          \
  __builtin_amdgcn_s_setprio(0);

#define TILE(T, BI)                                                          \
  {                                                                          \
    const char* L = (const char*)&lds[BI][0];                                \
    bf16x8 bfr[4][2];                                                        \
    _Pragma("unroll")                                                        \
    for (int nr = 0; nr < 4; ++nr) {                                         \
      bfr[nr][0] = *(const bf16x8*)(L + bro + nr * 2048 + cs0);              \
      bfr[nr][1] = *(const bf16x8*)(L + bro + nr * 2048 + cs1);              \
    }                                                                        \
    bf16x8 g0, g1, h0, h1;                                                   \
    g0 = *(const bf16x8*)(L + aro + 0 * 2048 + cs0);                         \
    g1 = *(const bf16x8*)(L + aro + 0 * 2048 + cs1);                         \
    h0 = *(const bf16x8*)(L + aro + 1 * 2048 + cs0);                         \
    h1 = *(const bf16x8*)(L + aro + 1 * 2048 + cs1);                         \
    asm volatile("s_waitcnt lgkmcnt(2)" ::: "memory");                       \
    __builtin_amdgcn_sched_barrier(0);                                       \
    MF(g0, g1, 0)                                                            \
    g0 = *(const bf16x8*)(L + aro + 2 * 2048 + cs0);                         \
    g1 = *(const bf16x8*)(L + aro + 2 * 2048 + cs1);                         \
    asm volatile("s_waitcnt lgkmcnt(2)" ::: "memory");                       \
    __builtin_amdgcn_sched_barrier(0);                                       \
    MF(h0, h1, 1)                                                            \
    h0 = *(const bf16x8*)(L + aro + 3 * 2048 + cs0);                         \
    h1 = *(const bf16x8*)(L + aro + 3 * 2048 + cs1);                         \
    asm volatile("s_waitcnt lgkmcnt(2)" ::: "memory");                       \
    __builtin_amdgcn_sched_barrier(0);                                       \
    MF(g0, g1, 2)                                                            \
    asm volatile("s_waitcnt lgkmcnt(0)" ::: "memory");                       \
    __builtin_amdgcn_sched_barrier(0);                                       \
    MF(h0, h1, 3)                                                            \
    if ((T) < 62) {                                                          \
      asm volatile("s_waitcnt vmcnt(6)" ::: "memory");                       \
    } else if ((T) == 62) {                                                  \
      asm volatile("s_waitcnt vmcnt(0)" ::: "memory");                       \
    }                                                                        \
    if ((T) < 63) __builtin_amdgcn_s_barrier();                              \
    if ((T) < 61) { STAGE((T) + 3, BI) }                                     \
  }

  STAGE(0, 0)
  STAGE(1, 1)
  STAGE(2, 2)
  asm volatile("s_waitcnt vmcnt(12)" ::: "memory");
  __builtin_amdgcn_s_barrier();

  #pragma clang loop unroll(disable)
  for (int t3 = 0; t3 < 63; t3 += 3) {
    TILE(t3 + 0, 0)
    TILE(t3 + 1, 1)
    TILE(t3 + 2, 2)
  }
  TILE(63, 0)

#undef STAGE
#undef TILE
#undef MF

  // epilogue: col 0..1023 = k (RoPE + nk), 1024..2047 = v (nv + vb^T)
  #pragma unroll
  for (int mr = 0; mr < 4; ++mr) {
    int mbase = tm * 256 + wm * 64 + mr * 16 + lg * 4;
    #pragma unroll
    for (int nr = 0; nr < 4; ++nr) {
      int col = tn * 128 + wn * 64 + nr * 16 + l15;
      float pv[4];
      #pragma unroll
      for (int r = 0; r < 4; ++r) pv[r] = __shfl_xor(acc[mr][nr][r], 1);
      #pragma unroll
      for (int r = 0; r < 4; ++r) {
        int m = mbase + r;
        float v = acc[mr][nr][r];
        int b = m >> 11;
        int s = m & 2047;
        if (col < 1024) {  // k: RoPE
          int h = col >> 7, d = col & 127;
          float x1 = (l15 & 1) ? pv[r] : v;
          float x2 = (l15 & 1) ? v : pv[r];
          float inv = __expf(-0.14391157f * (float)(d >> 1));
          float sn, cs;
          __sincosf((float)s * inv, &sn, &cs);
          float rr = (l15 & 1) ? (x1 * sn + x2 * cs) : (x1 * cs - x2 * sn);
          long o = ((long)((b * 8 + h) * 2048 + s)) * 128 + d;
          kb[o] = f2bf(rr);
          nk[o] = v;  // PRE-rope
        } else {
          int c2 = col - 1024;
          int h = c2 >> 7, d = c2 & 127;
          long o = ((long)((b * 8 + h) * 2048 + s)) * 128 + d;
          nv[o] = v;
          vb[((long)((b * 8 + h) * 128 + d)) * 2048 + s] = f2bf(v);  // [b][hkv][d][s]
        }
      }
    }
  }
}

// ---------------- Flash attention v8: 8 waves / 512 thr, Q-tile 256 ---------
__global__ __launch_bounds__(512) void flash_kernel(
    const short* __restrict__ qb, const short* __restrict__ kb,
    const short* __restrict__ vt, short* __restrict__ ao)
{
  const int bid = blockIdx.x;
  const int qt = 7 - (bid >> 6);    // LPT: heaviest blocks dispatch first
  const int hb = bid & 63;
  const int h = hb & 31, b = hb >> 5;
  const int hkv = h >> 2;
  const int tid = threadIdx.x, w = tid >> 6, lane = tid & 63;
  const int l31 = lane & 31, hi = lane >> 5;
  const int hi16 = hi * 16;
  const int q0 = qt * 256 + w * 32;
  const int q_abs = q0 + l31;

  const short* Q  = qb + (long)(b * 32 + h) * 2048 * 128;
  const char*  Kg = (const char*)(kb + (long)(b * 8 + hkv) * 2048 * 128);
  const char*  Vg = (const char*)(vt + (long)(b * 8 + hkv) * 2048 * 128);  // [d][s]

  __shared__ short Ks[2][64 * 128];  // [kv][d], 16B chunks XOR-swizzled (kv&15)
  __shared__ short Vs[2][128 * 64];  // [d][kv], 16B chunks XOR-swizzled (d&7)

  int skX[2], svRow[2], svCol[2], Xo[2];
  #pragma unroll
  for (int i2 = 0; i2 < 2; ++i2) {
    int X = tid * 16 + i2 * 8192;
    Xo[i2] = X;
    skX[i2] = X ^ (((X >> 8) & 15) << 4);
    int sv = X ^ (((X >> 7) & 7) << 4);
    svRow[i2] = sv >> 7;
    svCol[i2] = sv & 127;
  }

  bf16x8 qf[8];
  #pragma unroll
  for (int c = 0; c < 8; ++c)
    qf[c] = *(const bf16x8*)&Q[(long)q_abs * 128 + c * 16 + hi * 8];

  f32x16 o[4];
  #pragma unroll
  for (int db = 0; db < 4; ++db)
    #pragma unroll
    for (int r = 0; r < 16; ++r) o[db][r] = 0.f;
  float m_ = -3e38f, l_ = 0.f;

  const float scale2 = 0.08838834764831845f * 1.4426950408889634f;
  const int nt = 4 * (qt + 1);
  const int kswk = (l31 & 15) << 4;
  const int kswv = (l31 & 7) << 4;

  #pragma unroll
  for (int i2 = 0; i2 < 2; ++i2) {
    gload16(Kg + skX[i2], (char*)Ks[0] + Xo[i2]);
    gload16(Vg + ((long)svRow[i2] * 4096 + svCol[i2]), (char*)Vs[0] + Xo[i2]);
  }

  for (int t = 0; t < nt; ++t) {
    const int kv0 = t * 64;
    const int cur = t & 1;
    __syncthreads();
    if (t + 1 < nt) {
      const long kvb = (long)(kv0 + 64);
      #pragma unroll
      for (int i2 = 0; i2 < 2; ++i2) {
        gload16(Kg + kvb * 256 + skX[i2], (char*)Ks[cur ^ 1] + Xo[i2]);
        gload16(Vg + ((long)svRow[i2] * 4096 + kvb * 2 + svCol[i2]),
                (char*)Vs[cur ^ 1] + Xo[i2]);
      }
    }
    if (kv0 > q0 + 31) continue;

    f32x16 s0, s1;
    #pragma unroll
    for (int r = 0; r < 16; ++r) { s0[r] = 0.f; s1[r] = 0.f; }
    const char* kbase = (const char*)Ks[cur] + l31 * 256;
    __builtin_amdgcn_s_setprio(1);
    #pragma unroll
    for (int c = 0; c < 8; ++c) {
      bf16x8 kf0 = *(const bf16x8*)(kbase + ((c * 32 + hi16) ^ kswk));
      bf16x8 kf1 = *(const bf16x8*)(kbase + 8192 + ((c * 32 + hi16) ^ kswk));
      s0 = __builtin_amdgcn_mfma_f32_32x32x16_bf16(kf0, qf[c], s0, 0, 0, 0);
      s1 = __builtin_amdgcn_mfma_f32_32x32x16_bf16(kf1, qf[c], s1, 0, 0, 0);
    }
    __builtin_amdgcn_s_setprio(0);

    const bool diag = (kv0 + 63 > q0);
    if (diag) {
      #pragma unroll
      for (int r = 0; r < 16; ++r) {
        int krow = (r & 3) + 8 * (r >> 2) + 4 * hi;
        if (kv0 + krow > q_abs)      s0[r] = -3e38f;
        if (kv0 + 32 + krow > q_abs) s1[r] = -3e38f;
      }
    }
    // tree max
    float tm_[8];
    #pragma unroll
    for (int r = 0; r < 8; ++r)
      tm_[r] = fmaxf(fmaxf(s0[r], s0[r + 8]), fmaxf(s1[r], s1[r + 8]));
    #pragma unroll
    for (int st = 4; st >= 1; st >>= 1)
      #pragma unroll
      for (int r = 0; r < st; ++r) tm_[r] = fmaxf(tm_[r], tm_[r + st]);
    float mx = tm_[0] * scale2;
    mx = fmaxf(mx, __shfl_xor(mx, 32));
    int need = mx > m_ + 11.5f;
    if (__any(need)) {
      float mn = fmaxf(m_, mx);
      float fac = exp2f(m_ - mn);
      m_ = mn;
      l_ *= fac;
      #pragma unroll
      for (int db = 0; db < 4; ++db)
        #pragma unroll
        for (int r = 0; r < 16; ++r) o[db][r] *= fac;
    }
    // exp2 + tree sum
    float ts[8];
    #pragma unroll
    for (int r = 0; r < 16; ++r) {
      s0[r] = exp2f(fmaf(s0[r], scale2, -m_));
      s1[r] = exp2f(fmaf(s1[r], scale2, -m_));
    }
    #pragma unroll
    for (int r = 0; r < 8; ++r)
      ts[r] = (s0[r] + s0[r + 8]) + (s1[r] + s1[r + 8]);
    #pragma unroll
    for (int st = 4; st >= 1; st >>= 1)
      #pragma unroll
      for (int r = 0; r < st; ++r) ts[r] += ts[r + st];
    float rs = ts[0];
    rs += __shfl_xor(rs, 32);
    l_ += rs;

    const char* vbase = (const char*)Vs[cur] + l31 * 128;
    #pragma unroll
    for (int t2 = 0; t2 < 2; ++t2) {
      const f32x16 sp = t2 ? s1 : s0;
      unsigned wd[8];
      #pragma unroll
      for (int jj = 0; jj < 8; ++jj) wd[jj] = cvtpk(sp[2 * jj], sp[2 * jj + 1]);
      unsigned u0 = hi ? wd[0] : wd[2];
      unsigned u1 = hi ? wd[1] : wd[3];
      unsigned u2 = hi ? wd[4] : wd[6];
      unsigned u3 = hi ? wd[5] : wd[7];
      unsigned x0 = (unsigned)__shfl_xor((int)u0, 32);
      unsigned x1 = (unsigned)__shfl_xor((int)u1, 32);
      unsigned x2 = (unsigned)__shfl_xor((int)u2, 32);
      unsigned x3 = (unsigned)__shfl_xor((int)u3, 32);
      BW f0, f1;
      f0.u[0] = hi ? x0 : wd[0];
      f0.u[1] = hi ? x1 : wd[1];
      f0.u[2] = hi ? wd[2] : x0;
      f0.u[3] = hi ? wd[3] : x1;
      f1.u[0] = hi ? x2 : wd[4];
      f1.u[1] = hi ? x3 : wd[5];
      f1.u[2] = hi ? wd[6] : x2;
      f1.u[3] = hi ? wd[7] : x3;
      __builtin_amdgcn_s_setprio(1);
      #pragma unroll
      for (int cc = 0; cc < 2; ++cc) {
        const BW& fr = cc ? f1 : f0;
        #pragma unroll
        for (int db = 0; db < 4; ++db) {
          bf16x8 vf = *(const bf16x8*)(vbase + db * 4096 +
                                       ((t2 * 64 + cc * 32 + hi16) ^ kswv));
          o[db] = __builtin_amdgcn_mfma_f32_32x32x16_bf16(vf, fr.v, o[db], 0, 0, 0);
        }
      }
      __builtin_amdgcn_s_setprio(0);
    }
  }

  float invl = 1.0f / l_;
  const long aorow = ((long)(b * 2048 + q_abs)) * 4096 + h * 128 + hi * 4;
  #pragma unroll
  for (int db = 0; db < 4; ++db)
    #pragma unroll
    for (int r = 0; r < 16; ++r) {
      int doff = db * 32 + (r & 3) + 8 * (r >> 2);
      ao[aorow + doff] = f2bf(o[db][r] * invl);
    }
}

// ---------------- launcher --------------------------------------------------
extern "C" void kernel_launch(void* const* d_in, const int* in_sizes, int n_in,
                              void* d_out, int out_size, void* d_ws, size_t ws_size,
                              hipStream_t stream) {
  const float* x  = (const float*)d_in[0];
  const float* wq = (const float*)d_in[1];
  const float* wk = (const float*)d_in[2];
  const float* wv = (const float*)d_in[3];
  const float* wo = (const float*)d_in[4];
  float* out = (float*)d_out;

  char* ws = (char*)d_ws;
  short* xb    = (short*)(ws);               // x bf16; later reused as attn_out
  short* wqkvb = (short*)(ws + 33554432);    // wq|wk|wv bf16 (6144x4096)
  short* wob   = (short*)(ws + 83886080);
  short* qb    = (short*)(ws + 117440512);   // (B,H,S,D) post-RoPE
  short* kb    = (short*)(ws + 150994944);   // (B,Hkv,S,D) post-RoPE
  short* vb    = (short*)(ws + 159383552);   // (B,Hkv,D,S)  TRANSPOSED
  short* ao    = xb;

  float* nk = out + 16777216;  // new_k fp32 (B,Hkv,S,D) PRE-rope
  float* nv = out + 20971520;  // new_v fp32

  cast_all<<<28672, 256, 0, stream>>>(x, wq, wk, wv, wo, xb, wqkvb, wob);

  gemm_q<<<256, 512, 0, stream>>>(xb, wqkvb, qb);
  gemm_kv<<<256, 512, 0, stream>>>(xb, wqkvb + 16777216, kb, vb, nk, nv);
  flash_kernel<<<512, 512, 0, stream>>>(qb, kb, vb, ao);
  gemm_out<<<256, 512, 0, stream>>>(ao, wob, out);
}

// Round 19
// 478.471 us; speedup vs baseline: 1.1573x; 1.0005x over previous
//
#include <hip/hip_runtime.h>
#include <hip/hip_bf16.h>

typedef __attribute__((ext_vector_type(8)))  short   s16x8;
typedef __attribute__((ext_vector_type(8)))  __bf16  bf16x8;
typedef __attribute__((ext_vector_type(4)))  float   f32x4;
typedef __attribute__((ext_vector_type(16))) float   f32x16;

#define DEV static __device__ __forceinline__

DEV short f2bf(float f) {
  unsigned u = __builtin_bit_cast(unsigned, f);
  u = (u + 0x7fff + ((u >> 16) & 1)) >> 16;
  return (short)u;
}
DEV float bf2f(short s) {
  unsigned u = ((unsigned)(unsigned short)s) << 16;
  return __builtin_bit_cast(float, u);
}

DEV void gload16(const void* g, void* l) {
  __builtin_amdgcn_global_load_lds(
      (const __attribute__((address_space(1))) unsigned int*)g,
      (__attribute__((address_space(3))) unsigned int*)l, 16, 0, 0);
}

DEV unsigned cvtpk(float lo, float hi) {
  unsigned r;
  asm("v_cvt_pk_bf16_f32 %0, %1, %2" : "=v"(r) : "v"(lo), "v"(hi));
  return r;
}

typedef union { unsigned u[4]; bf16x8 v; } BW;

// ---------------- fused cast fp32 -> bf16 for all 5 inputs ------------------
__global__ __launch_bounds__(256) void cast_all(
    const float* __restrict__ x,  const float* __restrict__ wq,
    const float* __restrict__ wk, const float* __restrict__ wv,
    const float* __restrict__ wo,
    short* __restrict__ xb, short* __restrict__ wqkvb, short* __restrict__ wob) {
  long i = (long)blockIdx.x * 256 + threadIdx.x;  // vector index
  const float* src;
  short* dst;
  long off;
  if (i < 2097152)       { src = x;  dst = xb;               off = i; }
  else if (i < 4194304)  { src = wq; dst = wqkvb;            off = i - 2097152; }
  else if (i < 4718592)  { src = wk; dst = wqkvb + 16777216; off = i - 4194304; }
  else if (i < 5242880)  { src = wv; dst = wqkvb + 20971520; off = i - 4718592; }
  else                   { src = wo; dst = wob;              off = i - 5242880; }
  long e = off * 8;
  float4 a = *(const float4*)(src + e);
  float4 b = *(const float4*)(src + e + 4);
  s16x8 o;
  o[0] = f2bf(a.x); o[1] = f2bf(a.y); o[2] = f2bf(a.z); o[3] = f2bf(a.w);
  o[4] = f2bf(b.x); o[5] = f2bf(b.y); o[6] = f2bf(b.z); o[7] = f2bf(b.w);
  *(s16x8*)(dst + e) = o;
}

// ======== GEMM 256x256, BK=32, 3-buffer 1-barrier/tile engine ===============
// As R18 (proven) but A-read pipeline deepened to 3 OUTSTANDING:
// preload a0..a2; phase k issues a_{k+3}, waits lgkmcnt(3) (tail 2/1/0).
// 3 phases (~150cy MFMA) cover the ~120cy DS latency -> no per-phase stall.
// Per K-tile still ONE vmcnt(4) + ONE barrier + STAGE(t+3).
#define G_PROLOG                                                             \
  __shared__ __align__(16) short lds[3][16384];                              \
  const int tid = threadIdx.x;                                               \
  const int lane = tid & 63;                                                 \
  const int w = tid >> 6;                                                    \
  const int wm = w >> 2, wn = w & 3;                                         \
  const int l15 = lane & 15, lg = lane >> 4;                                 \
  int c = blockIdx.x & 7, j = blockIdx.x >> 3;                               \
  const int tm = (c >> 2) * 8 + (j & 7);                                     \
  const int tn = (c & 3) * 4 + (j >> 3);                                     \
  const char* Ac = (const char*)A;                                           \
  const char* Wc = (const char*)W;                                           \
  int Xl[2];                                                                 \
  long aSrc[2], bSrc[2];                                                     \
  _Pragma("unroll")                                                          \
  for (int q = 0; q < 2; ++q) {                                              \
    int X = tid * 16 + q * 8192;                                             \
    int row = X >> 6;                                                        \
    int colS = (X & 63) ^ (((X >> 7) & 3) << 4);                             \
    Xl[q] = X;                                                               \
    aSrc[q] = (long)(tm * 256 + row) * 8192 + colS;                          \
    bSrc[q] = (long)(tn * 256 + row) * 8192 + colS;                          \
  }                                                                          \
  f32x4 zero = {0.f, 0.f, 0.f, 0.f};                                         \
  f32x4 acc[8][4];                                                           \
  _Pragma("unroll")                                                          \
  for (int i = 0; i < 8; ++i)                                                \
    _Pragma("unroll")                                                        \
    for (int jj = 0; jj < 4; ++jj) acc[i][jj] = zero;                        \
  const int rcol = (lg << 4) ^ (((l15 >> 1) & 3) << 4);                      \
  const int aBase = (wm * 128 + l15) * 64 + rcol;                            \
  const int bBase = 16384 + (wn * 64 + l15) * 64 + rcol;

#define G_STAGE(TT, BI)                                                      \
  {                                                                          \
    const long kof_ = (long)(TT) * 64;                                       \
    _Pragma("unroll")                                                        \
    for (int q = 0; q < 2; ++q)                                              \
      gload16(Ac + aSrc[q] + kof_, (char*)&lds[BI][0] + Xl[q]);              \
    _Pragma("unroll")                                                        \
    for (int q = 0; q < 2; ++q)                                              \
      gload16(Wc + bSrc[q] + kof_, (char*)&lds[BI][0] + 16384 + Xl[q]);      \
  }

#define G_MF4(AX, MR)                                                        \
  __builtin_amdgcn_s_setprio(1);                                             \
  acc[MR][0] = __builtin_amdgcn_mfma_f32_16x16x32_bf16(AX, bfr0, acc[MR][0], 0, 0, 0); \
  acc[MR][1] = __builtin_amdgcn_mfma_f32_16x16x32_bf16(AX, bfr1, acc[MR][1], 0, 0, 0); \
  acc[MR][2] = __builtin_amdgcn_mfma_f32_16x16x32_bf16(AX, bfr2, acc[MR][2], 0, 0, 0); \
  acc[MR][3] = __builtin_amdgcn_mfma_f32_16x16x32_bf16(AX, bfr3, acc[MR][3], 0, 0, 0); \
  __builtin_amdgcn_s_setprio(0);

// phase with a lookahead issue (k = 0..4 issue a_{k+3}) then counted wait
#define G_PH(AK, MR, ISSUE, WAITN)                                           \
  ISSUE                                                                      \
  asm volatile("s_waitcnt lgkmcnt(" #WAITN ")" ::: "memory");                \
  __builtin_amdgcn_sched_barrier(0);                                         \
  G_MF4(AK, MR)

#define G_RD(AK, K)  AK = *(const bf16x8*)(LA + aBase + (K) * 1024);

#define G_TILE(T, BI)                                                        \
  {                                                                          \
    const char* LA = (const char*)&lds[BI][0];                               \
    bf16x8 bfr0 = *(const bf16x8*)(LA + bBase + 0 * 1024);                   \
    bf16x8 bfr1 = *(const bf16x8*)(LA + bBase + 1 * 1024);                   \
    bf16x8 bfr2 = *(const bf16x8*)(LA + bBase + 2 * 1024);                   \
    bf16x8 bfr3 = *(const bf16x8*)(LA + bBase + 3 * 1024);                   \
    bf16x8 a0, a1, a2, a3, a4, a5, a6, a7;                                   \
    G_RD(a0, 0) G_RD(a1, 1) G_RD(a2, 2)                                      \
    G_PH(a0, 0, G_RD(a3, 3), 3)                                              \
    G_PH(a1, 1, G_RD(a4, 4), 3)                                              \
    G_PH(a2, 2, G_RD(a5, 5), 3)                                              \
    G_PH(a3, 3, G_RD(a6, 6), 3)                                              \
    G_PH(a4, 4, G_RD(a7, 7), 3)                                              \
    G_PH(a5, 5, , 2)                                                         \
    G_PH(a6, 6, , 1)                                                         \
    G_PH(a7, 7, , 0)                                                         \
    if ((T) < 126) {                                                         \
      asm volatile("s_waitcnt vmcnt(4)" ::: "memory");                       \
    } else if ((T) == 126) {                                                 \
      asm volatile("s_waitcnt vmcnt(0)" ::: "memory");                       \
    }                                                                        \
    if ((T) < 127) __builtin_amdgcn_s_barrier();                             \
    if ((T) < 125) { G_STAGE((T) + 3, BI) }                                  \
  }

#define G_LOOP                                                               \
  G_STAGE(0, 0)                                                              \
  G_STAGE(1, 1)                                                              \
  G_STAGE(2, 2)                                                              \
  asm volatile("s_waitcnt vmcnt(8)" ::: "memory");                           \
  __builtin_amdgcn_s_barrier();                                              \
  _Pragma("clang loop unroll(disable)")                                      \
  for (int t3 = 0; t3 < 126; t3 += 3) {                                      \
    G_TILE(t3 + 0, 0)                                                        \
    G_TILE(t3 + 1, 1)                                                        \
    G_TILE(t3 + 2, 2)                                                        \
  }                                                                          \
  G_TILE(126, 0)                                                             \
  G_TILE(127, 1)

// ---------------- GEMM-Q: q projection + RoPE epilogue ----------------------
__global__ __launch_bounds__(512, 2) void gemm_q(
    const short* __restrict__ A, const short* __restrict__ W,
    short* __restrict__ qb)
{
  G_PROLOG
  G_LOOP
  // epilogue: all columns are q -> RoPE (pair = adjacent l15 lane) + write qb
  #pragma unroll
  for (int mr = 0; mr < 8; ++mr) {
    int mbase = tm * 256 + wm * 128 + mr * 16 + lg * 4;
    #pragma unroll
    for (int nr = 0; nr < 4; ++nr) {
      int col = tn * 256 + wn * 64 + nr * 16 + l15;
      float pv[4];
      #pragma unroll
      for (int r = 0; r < 4; ++r) pv[r] = __shfl_xor(acc[mr][nr][r], 1);
      #pragma unroll
      for (int r = 0; r < 4; ++r) {
        int m = mbase + r;
        float v = acc[mr][nr][r];
        int b = m >> 11;
        int s = m & 2047;
        int h = col >> 7, d = col & 127;
        float x1 = (l15 & 1) ? pv[r] : v;
        float x2 = (l15 & 1) ? v : pv[r];
        float inv = __expf(-0.14391157f * (float)(d >> 1));
        float sn, cs;
        __sincosf((float)s * inv, &sn, &cs);
        float rr = (l15 & 1) ? (x1 * sn + x2 * cs) : (x1 * cs - x2 * sn);
        qb[((long)((b * 32 + h) * 2048 + s)) * 128 + d] = f2bf(rr);
      }
    }
  }
}

// ---------------- GEMM-OUT: out projection, plain fp32 epilogue -------------
__global__ __launch_bounds__(512, 2) void gemm_out(
    const short* __restrict__ A, const short* __restrict__ W,
    float* __restrict__ Cout)
{
  G_PROLOG
  G_LOOP
  #pragma unroll
  for (int mr = 0; mr < 8; ++mr) {
    int mbase = tm * 256 + wm * 128 + mr * 16 + lg * 4;
    #pragma unroll
    for (int nr = 0; nr < 4; ++nr) {
      int col = tn * 256 + wn * 64 + nr * 16 + l15;
      #pragma unroll
      for (int r = 0; r < 4; ++r)
        Cout[(long)(mbase + r) * 4096 + col] = acc[mr][nr][r];
    }
  }
}

#undef G_PROLOG
#undef G_STAGE
#undef G_TILE
#undef G_MF4
#undef G_PH
#undef G_RD
#undef G_LOOP

// ---------------- GEMM-KV: 256x128, BK=64, 3-buffer (proven), N=2048 --------
__global__ __launch_bounds__(512, 2) void gemm_kv(
    const short* __restrict__ A, const short* __restrict__ W,
    short* __restrict__ kb, short* __restrict__ vb,
    float* __restrict__ nk, float* __restrict__ nv)
{
  __shared__ short lds[3][24576];  // 3 x 48KB: A at +0 (32KB), B at +32768

  const int tid = threadIdx.x;
  const int lane = tid & 63;
  const int w = tid >> 6;
  const int wm = w >> 1, wn = w & 1;          // 4 x 2 waves
  const int l15 = lane & 15, lg = lane >> 4;
  const int swz = (l15 & 7) << 4;

  int c = blockIdx.x & 7, j = blockIdx.x >> 3;
  const int tm = (c >> 2) * 8 + (j & 7);
  const int tn = (c & 3) * 4 + (j >> 3);     // 16 tn tiles of 128

  const char* Ac = (const char*)A;
  const char* Wc = (const char*)W;

  int aXo[4], bXo[2];
  long aSrc[4], bSrc[2];
  #pragma unroll
  for (int l4 = 0; l4 < 4; ++l4) {
    int X = tid * 16 + l4 * 8192;
    int row = X >> 7;
    int colS = (X & 127) ^ (((X >> 7) & 7) << 4);
    aXo[l4] = X;
    aSrc[l4] = (long)(tm * 256 + row) * 8192 + colS;
  }
  #pragma unroll
  for (int l4 = 0; l4 < 2; ++l4) {
    int X = tid * 16 + l4 * 8192;
    int row = X >> 7;
    int colS = (X & 127) ^ (((X >> 7) & 7) << 4);
    bXo[l4] = X;
    bSrc[l4] = (long)(tn * 128 + row) * 8192 + colS;
  }

#define STAGE(TT, BI)                                                        \
  {                                                                          \
    const long kof_ = (long)(TT) * 128;                                      \
    _Pragma("unroll")                                                        \
    for (int l4 = 0; l4 < 4; ++l4)                                           \
      gload16(Ac + aSrc[l4] + kof_, (char*)&lds[BI][0] + aXo[l4]);           \
    _Pragma("unroll")                                                        \
    for (int l4 = 0; l4 < 2; ++l4)                                           \
      gload16(Wc + bSrc[l4] + kof_, (char*)&lds[BI][0] + 32768 + bXo[l4]);   \
  }

  f32x4 zero = {0.f, 0.f, 0.f, 0.f};
  f32x4 acc[4][4];
  #pragma unroll
  for (int i = 0; i < 4; ++i)
    #pragma unroll
    for (int jj = 0; jj < 4; ++jj) acc[i][jj] = zero;

  const int aro = (wm * 64 + l15) * 128;
  const int bro = 32768 + (wn * 64 + l15) * 128;
  const int cs0 = (lg << 4) ^ swz;
  const int cs1 = (64 | (lg << 4)) ^ swz;

#define MF(a0, a1, MR)                                                       \
  __builtin_amdgcn_s_setprio(1);                                             \
  _Pragma("unroll")                                                          \
  for (int nr = 0; nr < 4; ++nr) {                                           \
    acc[MR][nr] = __builtin_amdgcn_mfma_f32_16x16x32_bf16(                   \
        a0, bfr[nr][0], acc[MR][nr], 0, 0, 0);                               \
    acc[MR][nr] = __builtin_amdgcn_mfma_f32_16x16x32_bf16(                   \
        a1, bfr[nr][1], acc[MR][nr], 0, 0, 0);                               \
  }                                                                          \
  __builtin_amdgcn_s_setprio(0);

#define TILE(T, BI)                                                          \
  {                                                                          \
    const char* L = (const char*)&lds[BI][0];                                \
    bf16x8 bfr[4][2];                                                        \
    _Pragma("unroll")                                                        \
    for (int nr = 0; nr < 4; ++nr) {                                         \
      bfr[nr][0] = *(const bf16x8*)(L + bro + nr * 2048 + cs0);              \
      bfr[nr][1] = *(const bf16x8*)(L + bro + nr * 2048 + cs1);              \
    }                                                                        \
    bf16x8 g0, g1, h0, h1;                                                   \
    g0 = *(const bf16x8*)(L + aro + 0 * 2048 + cs0);                         \
    g1 = *(const bf16x8*)(L + aro + 0 * 2048 + cs1);                         \
    h0 = *(const bf16x8*)(L + aro + 1 * 2048 + cs0);                         \
    h1 = *(const bf16x8*)(L + aro + 1 * 2048 + cs1);                         \
    asm volatile("s_waitcnt lgkmcnt(2)" ::: "memory");                       \
    __builtin_amdgcn_sched_barrier(0);                                       \
    MF(g0, g1, 0)                                                            \
    g0 = *(const bf16x8*)(L + aro + 2 * 2048 + cs0);                         \
    g1 = *(const bf16x8*)(L + aro + 2 * 2048 + cs1);                         \
    asm volatile("s_waitcnt lgkmcnt(2)" ::: "memory");                       \
    __builtin_amdgcn_sched_barrier(0);                                       \
    MF(h0, h1, 1)                                                            \
    h0 = *(const bf16x8*)(L + aro + 3 * 2048 + cs0);                         \
    h1 = *(const bf16x8*)(L + aro + 3 * 2048 + cs1);                         \
    asm volatile("s_waitcnt lgkmcnt(2)" ::: "memory");                       \
    __builtin_amdgcn_sched_barrier(0);                                       \
    MF(g0, g1, 2)                                                            \
    asm volatile("s_waitcnt lgkmcnt(0)" ::: "memory");                       \
    __builtin_amdgcn_sched_barrier(0);                                       \
    MF(h0, h1, 3)                                                            \
    if ((T) < 62) {                                                          \
      asm volatile("s_waitcnt vmcnt(6)" ::: "memory");                       \
    } else if ((T) == 62) {                                                  \
      asm volatile("s_waitcnt vmcnt(0)" ::: "memory");                       \
    }                                                                        \
    if ((T) < 63) __builtin_amdgcn_s_barrier();                              \
    if ((T) < 61) { STAGE((T) + 3, BI) }                                     \
  }

  STAGE(0, 0)
  STAGE(1, 1)
  STAGE(2, 2)
  asm volatile("s_waitcnt vmcnt(12)" ::: "memory");
  __builtin_amdgcn_s_barrier();

  #pragma clang loop unroll(disable)
  for (int t3 = 0; t3 < 63; t3 += 3) {
    TILE(t3 + 0, 0)
    TILE(t3 + 1, 1)
    TILE(t3 + 2, 2)
  }
  TILE(63, 0)

#undef STAGE
#undef TILE
#undef MF

  // epilogue: col 0..1023 = k (RoPE + nk), 1024..2047 = v (nv + vb^T)
  #pragma unroll
  for (int mr = 0; mr < 4; ++mr) {
    int mbase = tm * 256 + wm * 64 + mr * 16 + lg * 4;
    #pragma unroll
    for (int nr = 0; nr < 4; ++nr) {
      int col = tn * 128 + wn * 64 + nr * 16 + l15;
      float pv[4];
      #pragma unroll
      for (int r = 0; r < 4; ++r) pv[r] = __shfl_xor(acc[mr][nr][r], 1);
      #pragma unroll
      for (int r = 0; r < 4; ++r) {
        int m = mbase + r;
        float v = acc[mr][nr][r];
        int b = m >> 11;
        int s = m & 2047;
        if (col < 1024) {  // k: RoPE
          int h = col >> 7, d = col & 127;
          float x1 = (l15 & 1) ? pv[r] : v;
          float x2 = (l15 & 1) ? v : pv[r];
          float inv = __expf(-0.14391157f * (float)(d >> 1));
          float sn, cs;
          __sincosf((float)s * inv, &sn, &cs);
          float rr = (l15 & 1) ? (x1 * sn + x2 * cs) : (x1 * cs - x2 * sn);
          long o = ((long)((b * 8 + h) * 2048 + s)) * 128 + d;
          kb[o] = f2bf(rr);
          nk[o] = v;  // PRE-rope
        } else {
          int c2 = col - 1024;
          int h = c2 >> 7, d = c2 & 127;
          long o = ((long)((b * 8 + h) * 2048 + s)) * 128 + d;
          nv[o] = v;
          vb[((long)((b * 8 + h) * 128 + d)) * 2048 + s] = f2bf(v);  // [b][hkv][d][s]
        }
      }
    }
  }
}

// ---------------- Flash attention v9: 8 waves, XCD-local KV groups ----------
// grid 512; bid = qtIdx*64 + r with qt = 7-qtIdx (LPT). r remapped so XCD
// c = r&7 owns (b,hkv) groups {2c, 2c+1} (2MB KV, L2-resident):
//   u = r>>3; g = c*2 + (u>>2); member = u&3; b = g>>3; hkv = g&7;
//   h = hkv*4 + member.   (bijective r <-> (b,h))
__global__ __launch_bounds__(512) void flash_kernel(
    const short* __restrict__ qb, const short* __restrict__ kb,
    const short* __restrict__ vt, short* __restrict__ ao)
{
  const int bid = blockIdx.x;
  const int qt = 7 - (bid >> 6);    // LPT: heaviest blocks dispatch first
  const int r_ = bid & 63;
  const int cx = r_ & 7, u_ = r_ >> 3;
  const int g_ = cx * 2 + (u_ >> 2);
  const int b = g_ >> 3, hkv = g_ & 7;
  const int h = hkv * 4 + (u_ & 3);
  const int tid = threadIdx.x, w = tid >> 6, lane = tid & 63;
  const int l31 = lane & 31, hi = lane >> 5;
  const int hi16 = hi * 16;
  const int q0 = qt * 256 + w * 32;
  const int q_abs = q0 + l31;

  const short* Q  = qb + (long)(b * 32 + h) * 2048 * 128;
  const char*  Kg = (const char*)(kb + (long)(b * 8 + hkv) * 2048 * 128);
  const char*  Vg = (const char*)(vt + (long)(b * 8 + hkv) * 2048 * 128);  // [d][s]

  __shared__ short Ks[2][64 * 128];  // [kv][d], 16B chunks XOR-swizzled (kv&15)
  __shared__ short Vs[2][128 * 64];  // [d][kv], 16B chunks XOR-swizzled (d&7)

  int skX[2], svRow[2], svCol[2], Xo[2];
  #pragma unroll
  for (int i2 = 0; i2 < 2; ++i2) {
    int X = tid * 16 + i2 * 8192;
    Xo[i2] = X;
    skX[i2] = X ^ (((X >> 8) & 15) << 4);
    int sv = X ^ (((X >> 7) & 7) << 4);
    svRow[i2] = sv >> 7;
    svCol[i2] = sv & 127;
  }

  bf16x8 qf[8];
  #pragma unroll
  for (int c = 0; c < 8; ++c)
    qf[c] = *(const bf16x8*)&Q[(long)q_abs * 128 + c * 16 + hi * 8];

  f32x16 o[4];
  #pragma unroll
  for (int db = 0; db < 4; ++db)
    #pragma unroll
    for (int r = 0; r < 16; ++r) o[db][r] = 0.f;
  float m_ = -3e38f, l_ = 0.f;

  const float scale2 = 0.08838834764831845f * 1.4426950408889634f;
  const int nt = 4 * (qt + 1);
  const int kswk = (l31 & 15) << 4;
  const int kswv = (l31 & 7) << 4;

  #pragma unroll
  for (int i2 = 0; i2 < 2; ++i2) {
    gload16(Kg + skX[i2], (char*)Ks[0] + Xo[i2]);
    gload16(Vg + ((long)svRow[i2] * 4096 + svCol[i2]), (char*)Vs[0] + Xo[i2]);
  }

  for (int t = 0; t < nt; ++t) {
    const int kv0 = t * 64;
    const int cur = t & 1;
    __syncthreads();
    if (t + 1 < nt) {
      const long kvb = (long)(kv0 + 64);
      #pragma unroll
      for (int i2 = 0; i2 < 2; ++i2) {
        gload16(Kg + kvb * 256 + skX[i2], (char*)Ks[cur ^ 1] + Xo[i2]);
        gload16(Vg + ((long)svRow[i2] * 4096 + kvb * 2 + svCol[i2]),
                (char*)Vs[cur ^ 1] + Xo[i2]);
      }
    }
    if (kv0 > q0 + 31) continue;

    f32x16 s0, s1;
    #pragma unroll
    for (int r = 0; r < 16; ++r) { s0[r] = 0.f; s1[r] = 0.f; }
    const char* kbase = (const char*)Ks[cur] + l31 * 256;
    __builtin_amdgcn_s_setprio(1);
    #pragma unroll
    for (int c = 0; c < 8; ++c) {
      bf16x8 kf0 = *(const bf16x8*)(kbase + ((c * 32 + hi16) ^ kswk));
      bf16x8 kf1 = *(const bf16x8*)(kbase + 8192 + ((c * 32 + hi16) ^ kswk));
      s0 = __builtin_amdgcn_mfma_f32_32x32x16_bf16(kf0, qf[c], s0, 0, 0, 0);
      s1 = __builtin_amdgcn_mfma_f32_32x32x16_bf16(kf1, qf[c], s1, 0, 0, 0);
    }
    __builtin_amdgcn_s_setprio(0);

    const bool diag = (kv0 + 63 > q0);
    if (diag) {
      #pragma unroll
      for (int r = 0; r < 16; ++r) {
        int krow = (r & 3) + 8 * (r >> 2) + 4 * hi;
        if (kv0 + krow > q_abs)      s0[r] = -3e38f;
        if (kv0 + 32 + krow > q_abs) s1[r] = -3e38f;
      }
    }
    // tree max
    float tm_[8];
    #pragma unroll
    for (int r = 0; r < 8; ++r)
      tm_[r] = fmaxf(fmaxf(s0[r], s0[r + 8]), fmaxf(s1[r], s1[r + 8]));
    #pragma unroll
    for (int st = 4; st >= 1; st >>= 1)
      #pragma unroll
      for (int r = 0; r < st; ++r) tm_[r] = fmaxf(tm_[r], tm_[r + st]);
    float mx = tm_[0] * scale2;
    mx = fmaxf(mx, __shfl_xor(mx, 32));
    int need = mx > m_ + 11.5f;
    if (__any(need)) {
      float mn = fmaxf(m_, mx);
      float fac = exp2f(m_ - mn);
      m_ = mn;
      l_ *= fac;
      #pragma unroll
      for (int db = 0; db < 4; ++db)
        #pragma unroll
        for (int r = 0; r < 16; ++r) o[db][r] *= fac;
    }
    // exp2 + tree sum
    float ts[8];
    #pragma unroll
    for (int r = 0; r < 16; ++r) {
      s0[r] = exp2f(fmaf(s0[r], scale2, -m_));
      s1[r] = exp2f(fmaf(s1[r], scale2, -m_));
    }
    #pragma unroll
    for (int r = 0; r < 8; ++r)
      ts[r] = (s0[r] + s0[r + 8]) + (s1[r] + s1[r + 8]);
    #pragma unroll
    for (int st = 4; st >= 1; st >>= 1)
      #pragma unroll
      for (int r = 0; r < st; ++r) ts[r] += ts[r + st];
    float rs = ts[0];
    rs += __shfl_xor(rs, 32);
    l_ += rs;

    const char* vbase = (const char*)Vs[cur] + l31 * 128;
    #pragma unroll
    for (int t2 = 0; t2 < 2; ++t2) {
      const f32x16 sp = t2 ? s1 : s0;
      unsigned wd[8];
      #pragma unroll
      for (int jj = 0; jj < 8; ++jj) wd[jj] = cvtpk(sp[2 * jj], sp[2 * jj + 1]);
      unsigned u0 = hi ? wd[0] : wd[2];
      unsigned u1 = hi ? wd[1] : wd[3];
      unsigned u2 = hi ? wd[4] : wd[6];
      unsigned u3 = hi ? wd[5] : wd[7];
      unsigned x0 = (unsigned)__shfl_xor((int)u0, 32);
      unsigned x1 = (unsigned)__shfl_xor((int)u1, 32);
      unsigned x2 = (unsigned)__shfl_xor((int)u2, 32);
      unsigned x3 = (unsigned)__shfl_xor((int)u3, 32);
      BW f0, f1;
      f0.u[0] = hi ? x0 : wd[0];
      f0.u[1] = hi ? x1 : wd[1];
      f0.u[2] = hi ? wd[2] : x0;
      f0.u[3] = hi ? wd[3] : x1;
      f1.u[0] = hi ? x2 : wd[4];
      f1.u[1] = hi ? x3 : wd[5];
      f1.u[2] = hi ? wd[6] : x2;
      f1.u[3] = hi ? wd[7] : x3;
      __builtin_amdgcn_s_setprio(1);
      #pragma unroll
      for (int cc = 0; cc < 2; ++cc) {
        const BW& fr = cc ? f1 : f0;
        #pragma unroll
        for (int db = 0; db < 4; ++db) {
          bf16x8 vf = *(const bf16x8*)(vbase + db * 4096 +
                                       ((t2 * 64 + cc * 32 + hi16) ^ kswv));
          o[db] = __builtin_amdgcn_mfma_f32_32x32x16_bf16(vf, fr.v, o[db], 0, 0, 0);
        }
      }
      __builtin_amdgcn_s_setprio(0);
    }
  }

  float invl = 1.0f / l_;
  const long aorow = ((long)(b * 2048 + q_abs)) * 4096 + h * 128 + hi * 4;
  #pragma unroll
  for (int db = 0; db < 4; ++db)
    #pragma unroll
    for (int r = 0; r < 16; ++r) {
      int doff = db * 32 + (r & 3) + 8 * (r >> 2);
      ao[aorow + doff] = f2bf(o[db][r] * invl);
    }
}

// ---------------- launcher --------------------------------------------------
extern "C" void kernel_launch(void* const* d_in, const int* in_sizes, int n_in,
                              void* d_out, int out_size, void* d_ws, size_t ws_size,
                              hipStream_t stream) {
  const float* x  = (const float*)d_in[0];
  const float* wq = (const float*)d_in[1];
  const float* wk = (const float*)d_in[2];
  const float* wv = (const float*)d_in[3];
  const float* wo = (const float*)d_in[4];
  float* out = (float*)d_out;

  char* ws = (char*)d_ws;
  short* xb    = (short*)(ws);               // x bf16; later reused as attn_out
  short* wqkvb = (short*)(ws + 33554432);    // wq|wk|wv bf16 (6144x4096)
  short* wob   = (short*)(ws + 83886080);
  short* qb    = (short*)(ws + 117440512);   // (B,H,S,D) post-RoPE
  short* kb    = (short*)(ws + 150994944);   // (B,Hkv,S,D) post-RoPE
  short* vb    = (short*)(ws + 159383552);   // (B,Hkv,D,S)  TRANSPOSED
  short* ao    = xb;

  float* nk = out + 16777216;  // new_k fp32 (B,Hkv,S,D) PRE-rope
  float* nv = out + 20971520;  // new_v fp32

  cast_all<<<28672, 256, 0, stream>>>(x, wq, wk, wv, wo, xb, wqkvb, wob);

  gemm_q<<<256, 512, 0, stream>>>(xb, wqkvb, qb);
  gemm_kv<<<256, 512, 0, stream>>>(xb, wqkvb + 16777216, kb, vb, nk, nv);
  flash_kernel<<<512, 512, 0, stream>>>(qb, kb, vb, ao);
  gemm_out<<<256, 512, 0, stream>>>(ao, wob, out);
}